// Round 7
// baseline (425.106 us; speedup 1.0000x reference)
//
#include <hip/hip_runtime.h>

typedef unsigned short u16;
typedef unsigned int uint;
typedef __attribute__((ext_vector_type(4))) float floatx4;
typedef __attribute__((ext_vector_type(16))) float floatx16;
typedef __attribute__((ext_vector_type(8))) short shortx8;

// ---------- helpers ----------
__device__ __forceinline__ u16 f2b(float f) {
    unsigned int u = __float_as_uint(f);
    unsigned int r = (u + 0x7fffu + ((u >> 16) & 1u)) >> 16;
    return (u16)r;
}
__device__ __forceinline__ float b2f(u16 u) {
    return __uint_as_float(((unsigned int)u) << 16);
}
__device__ __forceinline__ void gl_lds16(const u16* g, u16* l) {
    __builtin_amdgcn_global_load_lds(
        (const __attribute__((address_space(1))) void*)g,
        (__attribute__((address_space(3))) void*)l, 16, 0, 0);
}
__device__ __forceinline__ float gelu_f(float v) {
    float e = __expf(1.59576912f * v * (1.0f + 0.044715f * v * v));
    return v * e / (e + 1.0f);
}
// one 1024-float4 weight-cvt chunk (f32 -> bf16), 256 threads
__device__ __forceinline__ void cvt_block(const float* __restrict__ src,
                                          u16* __restrict__ dst, int i0) {
    int i = i0 * 256 + threadIdx.x;
    float4 v = ((const float4*)src)[i];
    uint2 o;
    o.x = (uint)f2b(v.x) | ((uint)f2b(v.y) << 16);
    o.y = (uint)f2b(v.z) | ((uint)f2b(v.w) << 16);
    ((uint2*)dst)[i] = o;
}

// ---------- wave-per-row LN (C=512): 8 elems/lane, shuffle-only ----------
__device__ __forceinline__ void ln_row_wave_f32(const float* __restrict__ x,
                                                const float* __restrict__ w,
                                                const float* __restrict__ b,
                                                u16* __restrict__ out, int row) {
    int lane = threadIdx.x & 63;
    const float4* xr = (const float4*)(x + (size_t)row * 512);
    float4 v0 = xr[lane * 2], v1 = xr[lane * 2 + 1];
    float s = v0.x + v0.y + v0.z + v0.w + v1.x + v1.y + v1.z + v1.w;
    float s2 = v0.x * v0.x + v0.y * v0.y + v0.z * v0.z + v0.w * v0.w +
               v1.x * v1.x + v1.y * v1.y + v1.z * v1.z + v1.w * v1.w;
    #pragma unroll
    for (int o = 32; o > 0; o >>= 1) {
        s += __shfl_xor(s, o, 64);
        s2 += __shfl_xor(s2, o, 64);
    }
    float mu = s * (1.0f / 512.0f);
    float var = s2 * (1.0f / 512.0f) - mu * mu;
    float rstd = rsqrtf(var + 1e-5f);
    const float4* wr = (const float4*)w;
    const float4* br = (const float4*)b;
    float4 w0 = wr[lane * 2], w1 = wr[lane * 2 + 1];
    float4 b0 = br[lane * 2], b1 = br[lane * 2 + 1];
    uint4 o4;
    o4.x = (uint)f2b((v0.x - mu) * rstd * w0.x + b0.x) |
           ((uint)f2b((v0.y - mu) * rstd * w0.y + b0.y) << 16);
    o4.y = (uint)f2b((v0.z - mu) * rstd * w0.z + b0.z) |
           ((uint)f2b((v0.w - mu) * rstd * w0.w + b0.w) << 16);
    o4.z = (uint)f2b((v1.x - mu) * rstd * w1.x + b1.x) |
           ((uint)f2b((v1.y - mu) * rstd * w1.y + b1.y) << 16);
    o4.w = (uint)f2b((v1.z - mu) * rstd * w1.z + b1.z) |
           ((uint)f2b((v1.w - mu) * rstd * w1.w + b1.w) << 16);
    ((uint4*)(out + (size_t)row * 512))[lane] = o4;
}

// ---------- LN2: bf16 input, wave-per-row, 4 rows/block ----------
__global__ __launch_bounds__(256) void ln_kernel_b(const u16* __restrict__ x,
                                                   const float* __restrict__ w,
                                                   const float* __restrict__ b,
                                                   u16* __restrict__ out, int rep) {
    for (int rp = 0; rp < rep; ++rp) {
        int row = blockIdx.x * 4 + (threadIdx.x >> 6);
        int lane = threadIdx.x & 63;
        uint4 p = ((const uint4*)(x + (size_t)row * 512))[lane];
        float v[8];
        v[0] = b2f((u16)(p.x & 0xffffu)); v[1] = b2f((u16)(p.x >> 16));
        v[2] = b2f((u16)(p.y & 0xffffu)); v[3] = b2f((u16)(p.y >> 16));
        v[4] = b2f((u16)(p.z & 0xffffu)); v[5] = b2f((u16)(p.z >> 16));
        v[6] = b2f((u16)(p.w & 0xffffu)); v[7] = b2f((u16)(p.w >> 16));
        float s = 0.f, s2 = 0.f;
        #pragma unroll
        for (int i = 0; i < 8; i++) { s += v[i]; s2 += v[i] * v[i]; }
        #pragma unroll
        for (int o = 32; o > 0; o >>= 1) {
            s += __shfl_xor(s, o, 64);
            s2 += __shfl_xor(s2, o, 64);
        }
        float mu = s * (1.0f / 512.0f);
        float var = s2 * (1.0f / 512.0f) - mu * mu;
        float rstd = rsqrtf(var + 1e-5f);
        const float4* wr = (const float4*)w;
        const float4* br = (const float4*)b;
        float4 w0 = wr[lane * 2], w1 = wr[lane * 2 + 1];
        float4 b0 = br[lane * 2], b1 = br[lane * 2 + 1];
        float o8[8];
        o8[0] = (v[0] - mu) * rstd * w0.x + b0.x;
        o8[1] = (v[1] - mu) * rstd * w0.y + b0.y;
        o8[2] = (v[2] - mu) * rstd * w0.z + b0.z;
        o8[3] = (v[3] - mu) * rstd * w0.w + b0.w;
        o8[4] = (v[4] - mu) * rstd * w1.x + b1.x;
        o8[5] = (v[5] - mu) * rstd * w1.y + b1.y;
        o8[6] = (v[6] - mu) * rstd * w1.z + b1.z;
        o8[7] = (v[7] - mu) * rstd * w1.w + b1.w;
        uint4 o4;
        o4.x = (uint)f2b(o8[0]) | ((uint)f2b(o8[1]) << 16);
        o4.y = (uint)f2b(o8[2]) | ((uint)f2b(o8[3]) << 16);
        o4.z = (uint)f2b(o8[4]) | ((uint)f2b(o8[5]) << 16);
        o4.w = (uint)f2b(o8[6]) | ((uint)f2b(o8[7]) << 16);
        ((uint4*)(out + (size_t)row * 512))[lane] = o4;
    }
}

// ---------- prep: cvt wq + LN1 ----------
__global__ __launch_bounds__(256) void prep_kernel(
    const float* __restrict__ qkvw, u16* __restrict__ wq,
    const float* __restrict__ x, const float* __restrict__ n1w,
    const float* __restrict__ n1b, u16* __restrict__ hb, int rep) {
    for (int rp = 0; rp < rep; ++rp) {
        int bi = blockIdx.x;
        if (bi < 768) {
            cvt_block(qkvw, wq, bi);
        } else {
            int row = (bi - 768) * 4 + (threadIdx.x >> 6);
            ln_row_wave_f32(x, n1w, n1b, hb, row);
        }
    }
}

// ---------- GEMM A: 16x16x32 MFMA, MI=NI=4, dbuf, 128x128 BK=64 ----------
template <int EPI>
__global__ __launch_bounds__(256, 2) void gemm16(const u16* __restrict__ A,
                                                 const u16* __restrict__ W,
                                                 const float* __restrict__ bias,
                                                 u16* __restrict__ outB,
                                                 int M, int Nn, int K, int nby,
                                                 const float* __restrict__ cs0,
                                                 u16* __restrict__ cd0, int cn0,
                                                 const float* __restrict__ cs1,
                                                 u16* __restrict__ cd1, int cn1,
                                                 int rep) {
    constexpr int BM = 128, BN = 128, BK = 64;
    __shared__ u16 a_s[2][BM * BK];
    __shared__ u16 b_s[2][BN * BK];

    if ((int)blockIdx.y >= nby) {
        int flat = ((int)blockIdx.y - nby) * (int)gridDim.x + (int)blockIdx.x;
        for (int rp = 0; rp < rep; ++rp) {
            if (flat < cn0)            cvt_block(cs0, cd0, flat);
            else if (flat < cn0 + cn1) cvt_block(cs1, cd1, flat - cn0);
        }
        return;
    }

    int tid = threadIdx.x;
    int wid = tid >> 6, lane = tid & 63;
    int wm = wid >> 1, wn = wid & 1;
    int m_blk = blockIdx.x * BM;
    int n_blk = blockIdx.y * BN;
    int lr = lane & 15;
    int lkc = lane >> 4;

    const u16* Ag = A + (size_t)m_blk * K;
    const u16* Wg = W + (size_t)n_blk * K;

    int srow = tid >> 3;
    int skc = (tid & 7) ^ (srow & 7);

    auto stage = [&](int k0, int buf) {
        #pragma unroll
        for (int p = 0; p < 4; p++)
            gl_lds16(Ag + (size_t)(p * 32 + srow) * K + k0 + skc * 8,
                     a_s[buf] + (p * 256 + tid) * 8);
        #pragma unroll
        for (int p = 0; p < 4; p++)
            gl_lds16(Wg + (size_t)(p * 32 + srow) * K + k0 + skc * 8,
                     b_s[buf] + (p * 256 + tid) * 8);
    };

    for (int rp = 0; rp < rep; ++rp) {
        floatx4 acc[4][4];
        #pragma unroll
        for (int i = 0; i < 4; i++)
            #pragma unroll
            for (int j = 0; j < 4; j++) acc[i][j] = (floatx4){0.f, 0.f, 0.f, 0.f};

        stage(0, 0);
        int nit = K >> 6;
        for (int it = 0; it < nit; it++) {
            __syncthreads();
            if (it + 1 < nit) stage((it + 1) << 6, (it + 1) & 1);
            int cb = it & 1;
            #pragma unroll
            for (int s = 0; s < 2; s++) {
                int kc = s * 4 + lkc;
                shortx8 af[4], bf[4];
                #pragma unroll
                for (int i = 0; i < 4; i++) {
                    int row = wm * 64 + i * 16 + lr;
                    af[i] = *(const shortx8*)(a_s[cb] + (row * 8 + (kc ^ (row & 7))) * 8);
                }
                #pragma unroll
                for (int j = 0; j < 4; j++) {
                    int row = wn * 64 + j * 16 + lr;
                    bf[j] = *(const shortx8*)(b_s[cb] + (row * 8 + (kc ^ (row & 7))) * 8);
                }
                #pragma unroll
                for (int i = 0; i < 4; i++)
                    #pragma unroll
                    for (int j = 0; j < 4; j++)
                        acc[i][j] = __builtin_amdgcn_mfma_f32_16x16x32_bf16(
                            af[i], bf[j], acc[i][j], 0, 0, 0);
            }
        }

        int col_l = lane & 15;
        int row_base = (lane >> 4) * 4;
        #pragma unroll
        for (int nj = 0; nj < 4; nj++) {
            int col = n_blk + wn * 64 + nj * 16 + col_l;
            float bv = bias[col];
            #pragma unroll
            for (int mi = 0; mi < 4; mi++) {
                #pragma unroll
                for (int r = 0; r < 4; r++) {
                    int row = m_blk + wm * 64 + mi * 16 + row_base + r;
                    size_t off = (size_t)row * Nn + col;
                    float v = acc[mi][nj][r] + bv;
                    outB[off] = f2b(EPI == 2 ? gelu_f(v) : v);
                }
            }
        }
        __syncthreads();   // rep isolation: epilogue reads done before restage
    }
}

// ---------- GEMM B: 32x32x16, 64x64 block, BK=128, dbuf ----------
template <int EPI>
__global__ __launch_bounds__(256, 2) void gemm32(const u16* __restrict__ A,
                                                 const u16* __restrict__ W,
                                                 const float* __restrict__ bias,
                                                 const float* __restrict__ residF,
                                                 const u16* __restrict__ residB,
                                                 float* __restrict__ outF,
                                                 u16* __restrict__ outB,
                                                 int M, int Nn, int K, int rep) {
    constexpr int BM = 64, BN = 64, BK = 128;
    constexpr int CPR = BK / 8, KMSK = CPR - 1;
    __shared__ u16 a_s[2][BM * BK];
    __shared__ u16 b_s[2][BN * BK];

    int tid = threadIdx.x;
    int wid = tid >> 6, lane = tid & 63;
    int wm = wid >> 1, wn = wid & 1;
    int m_blk = blockIdx.x * BM;
    int n_blk = blockIdx.y * BN;
    int lr = lane & 31;
    int lk = lane >> 5;

    const u16* Ag = A + (size_t)m_blk * K;
    const u16* Wg = W + (size_t)n_blk * K;

    int srow = tid / CPR;
    int skc = (tid & KMSK) ^ (srow & KMSK);

    auto stage = [&](int k0, int buf) {
        #pragma unroll
        for (int p = 0; p < 4; p++)
            gl_lds16(Ag + (size_t)(p * 16 + srow) * K + k0 + skc * 8,
                     a_s[buf] + (p * 256 + tid) * 8);
        #pragma unroll
        for (int p = 0; p < 4; p++)
            gl_lds16(Wg + (size_t)(p * 16 + srow) * K + k0 + skc * 8,
                     b_s[buf] + (p * 256 + tid) * 8);
    };

    for (int rp = 0; rp < rep; ++rp) {
        floatx16 acc;
        #pragma unroll
        for (int r = 0; r < 16; r++) acc[r] = 0.f;

        stage(0, 0);
        int nit = K / BK;
        for (int it = 0; it < nit; it++) {
            __syncthreads();
            if (it + 1 < nit) stage((it + 1) * BK, (it + 1) & 1);
            int cb = it & 1;
            #pragma unroll
            for (int s = 0; s < BK / 16; s++) {
                int kc = s * 2 + lk;
                int arow = wm * 32 + lr;
                int brow = wn * 32 + lr;
                shortx8 af = *(const shortx8*)(a_s[cb] + (arow * CPR + (kc ^ (arow & KMSK))) * 8);
                shortx8 bf = *(const shortx8*)(b_s[cb] + (brow * CPR + (kc ^ (brow & KMSK))) * 8);
                acc = __builtin_amdgcn_mfma_f32_32x32x16_bf16(af, bf, acc, 0, 0, 0);
            }
        }

        int col_l = lane & 31;
        int row_q = 4 * (lane >> 5);
        int col = n_blk + wn * 32 + col_l;
        float bv = bias[col];
        #pragma unroll
        for (int r = 0; r < 16; r++) {
            int row = m_blk + wm * 32 + (r & 3) + 8 * (r >> 2) + row_q;
            size_t off = (size_t)row * Nn + col;
            float v = acc[r] + bv;
            if (EPI == 1) outB[off] = f2b(v + residF[off]);
            else          outF[off] = v + b2f(residB[off]);
        }
        __syncthreads();   // rep isolation
    }
}

// ---------- windowed attention, MFMA flash-style ----------
__global__ __launch_bounds__(256) void attn_kernel(const u16* __restrict__ qkv,
                                                   const float* __restrict__ rel_bias,
                                                   u16* __restrict__ out,
                                                   const float* __restrict__ csrc,
                                                   u16* __restrict__ cdst, int rep) {
    __shared__ u16 k_s[128][76];
    __shared__ u16 v_t[64][154];
    __shared__ u16 p_s[4][16][106];
    __shared__ float s_bias[64];

    int bx = blockIdx.x;
    if (bx >= 512) {                      // weight-cvt tail (w2)
        for (int rp = 0; rp < rep; ++rp) cvt_block(csrc, cdst, bx - 512);
        return;
    }
    int n = bx >> 8;
    int h = (bx >> 5) & 7;
    int t0 = (bx & 31) << 6;
    int tid = threadIdx.x, wid = tid >> 6, lane = tid & 63;
    int col = lane & 15, rq = lane >> 4;

    for (int rp = 0; rp < rep; ++rp) {
        __syncthreads();                  // rep isolation (no-op first iter)

        const u16* qrow = qkv + (size_t)(n * 2048 + t0 + wid * 16 + col) * 1536 + h * 64 + rq * 8;
        shortx8 qf0 = *(const shortx8*)qrow;
        shortx8 qf1 = *(const shortx8*)(qrow + 32);

        if (tid < 63) s_bias[tid] = rel_bias[h * 63 + tid];
        if (tid == 63) s_bias[63] = 0.f;

        const uint* qkv_u = (const uint*)qkv;
        for (int idx = tid; idx < 128 * 16; idx += 256) {
            int row = idx >> 4, j2 = idx & 15;
            int pos = t0 - 31 + row;
            uint2 kv; kv.x = 0u; kv.y = 0u;
            if (pos >= 0 && pos < 2048)
                kv = *(const uint2*)(qkv_u + (size_t)(n * 2048 + pos) * 768 + 256 + h * 32 + j2 * 2);
            *(uint2*)&k_s[row][j2 * 4] = kv;
        }
        for (int idx = tid; idx < 72 * 32; idx += 256) {
            int rpj = idx >> 5, j = idx & 31;
            int r0 = rpj * 2;
            int p0 = t0 - 31 + r0, p1 = p0 + 1;
            uint a = 0u, b = 0u;
            if (p0 >= 0 && p0 < 2048)
                a = qkv_u[(size_t)(n * 2048 + p0) * 768 + 512 + h * 32 + j];
            if (p1 >= 0 && p1 < 2048)
                b = qkv_u[(size_t)(n * 2048 + p1) * 768 + 512 + h * 32 + j];
            *(uint*)&v_t[2 * j][r0]     = (a & 0xffffu) | (b << 16);
            *(uint*)&v_t[2 * j + 1][r0] = (a >> 16) | (b & 0xffff0000u);
        }
        __syncthreads();

        floatx4 S[5];
        #pragma unroll
        for (int nt = 0; nt < 5; nt++) S[nt] = (floatx4){0.f, 0.f, 0.f, 0.f};
        #pragma unroll
        for (int nt = 0; nt < 5; nt++) {
            const u16* kb = &k_s[wid * 16 + nt * 16 + col][rq * 8];
            shortx8 b0 = *(const shortx8*)kb;
            shortx8 b1 = *(const shortx8*)(kb + 32);
            S[nt] = __builtin_amdgcn_mfma_f32_16x16x32_bf16(qf0, b0, S[nt], 0, 0, 0);
            S[nt] = __builtin_amdgcn_mfma_f32_16x16x32_bf16(qf1, b1, S[nt], 0, 0, 0);
        }

        #pragma unroll
        for (int r = 0; r < 4; r++) {
            int t_row = rq * 4 + r;
            float sc[5];
            float mx = -1e30f;
            #pragma unroll
            for (int nt = 0; nt < 5; nt++) {
                int w = nt * 16 + col - t_row;
                int pos_abs = t0 - 31 + wid * 16 + nt * 16 + col;
                float v;
                if (w < 0 || w > 62) {
                    v = -1e30f;
                } else {
                    v = S[nt][r] * 0.125f + s_bias[w];
                    if (pos_abs < 0 || pos_abs >= 2048) v -= 100.f;
                }
                sc[nt] = v;
                mx = fmaxf(mx, v);
            }
            #pragma unroll
            for (int o = 1; o < 16; o <<= 1) mx = fmaxf(mx, __shfl_xor(mx, o, 64));
            float l = 0.f;
            #pragma unroll
            for (int nt = 0; nt < 5; nt++) {
                sc[nt] = __expf(sc[nt] - mx);
                l += sc[nt];
            }
            #pragma unroll
            for (int o = 1; o < 16; o <<= 1) l += __shfl_xor(l, o, 64);
            float inv = 1.0f / l;
            #pragma unroll
            for (int nt = 0; nt < 5; nt++)
                p_s[wid][t_row][nt * 16 + col] = f2b(sc[nt] * inv);
            p_s[wid][t_row][80 + col] = 0;
        }
        __syncthreads();

        floatx4 O[4];
        #pragma unroll
        for (int dt = 0; dt < 4; dt++) O[dt] = (floatx4){0.f, 0.f, 0.f, 0.f};
        const u16* pr = &p_s[wid][col][rq * 8];
        shortx8 a0 = *(const shortx8*)pr;
        shortx8 a1 = *(const shortx8*)(pr + 32);
        shortx8 a2 = *(const shortx8*)(pr + 64);
        #pragma unroll
        for (int dt = 0; dt < 4; dt++) {
            const u16* vb = &v_t[dt * 16 + col][wid * 16 + rq * 8];
            shortx8 b0 = *(const shortx8*)vb;
            shortx8 b1 = *(const shortx8*)(vb + 32);
            shortx8 b2 = *(const shortx8*)(vb + 64);
            O[dt] = __builtin_amdgcn_mfma_f32_16x16x32_bf16(a0, b0, O[dt], 0, 0, 0);
            O[dt] = __builtin_amdgcn_mfma_f32_16x16x32_bf16(a1, b1, O[dt], 0, 0, 0);
            O[dt] = __builtin_amdgcn_mfma_f32_16x16x32_bf16(a2, b2, O[dt], 0, 0, 0);
        }

        #pragma unroll
        for (int dt = 0; dt < 4; dt++) {
            #pragma unroll
            for (int r = 0; r < 4; r++) {
                int t_row = rq * 4 + r;
                out[(size_t)(n * 2048 + t0 + wid * 16 + t_row) * 512 + h * 64 + dt * 16 + col] =
                    f2b(O[dt][r]);
            }
        }
    }
}

// ---------- launcher ----------
extern "C" void kernel_launch(void* const* d_in, const int* in_sizes, int n_in,
                              void* d_out, int out_size, void* d_ws, size_t ws_size,
                              hipStream_t stream) {
    const float* x     = (const float*)d_in[0];
    const float* n1w   = (const float*)d_in[1];
    const float* n1b   = (const float*)d_in[2];
    const float* qkvw  = (const float*)d_in[3];
    const float* qkvbv = (const float*)d_in[4];
    const float* relb  = (const float*)d_in[5];
    const float* projw = (const float*)d_in[6];
    const float* projb = (const float*)d_in[7];
    const float* n2w   = (const float*)d_in[8];
    const float* n2b   = (const float*)d_in[9];
    const float* fc1w  = (const float*)d_in[10];
    const float* fc1b  = (const float*)d_in[11];
    const float* fc2w  = (const float*)d_in[12];
    const float* fc2b  = (const float*)d_in[13];
    float* out = (float*)d_out;

    char* p = (char*)d_ws;
    u16* wq   = (u16*)p;  p += (size_t)786432 * 2;   // qkv_w bf16 (1536x512)
    u16* wp   = (u16*)p;  p += (size_t)262144 * 2;   // proj_w bf16 (512x512)
    u16* w1   = (u16*)p;  p += (size_t)1048576 * 2;  // fc1_w bf16 (2048x512)
    u16* w2   = (u16*)p;  p += (size_t)1048576 * 2;  // fc2_w bf16 (512x2048)
    u16* hb   = (u16*)p;  p += (size_t)2097152 * 2;  // h / h2 bf16 (4096x512)
    u16* qkvb = (u16*)p;  p += (size_t)6291456 * 2;  // qkv bf16 (4096x1536)
    u16* attb = (u16*)p;  p += (size_t)2097152 * 2;  // attn out bf16 (4096x512)
    u16* x2b  = (u16*)p;  p += (size_t)2097152 * 2;  // x + proj(attn), bf16
    u16* mb   = (u16*)p;  p += (size_t)8388608 * 2;  // gelu(fc1) bf16 (4096x2048)

    // INSTRUMENTATION ROUND: every phase repeated REP times (idempotent).
    // Purpose: lift the true slowest phase(s) above the 46us harness fills in
    // the rocprof top-5 (per-phase MfmaUtil/VALUBusy/conflicts/occupancy),
    // and split total into phase-work vs node-boundary overhead:
    //   Sum(t_i) ~= (dur_R7 - 164.7)/(REP-1);  OH ~= 164.7 - Sum(t_i).
    const int REP = 6;

    prep_kernel<<<1792, 256, 0, stream>>>(qkvw, wq, x, n1w, n1b, hb, REP);
    gemm16<0><<<dim3(32, 12 + 40), 256, 0, stream>>>(hb, wq, qkvbv, qkvb,
                                                     4096, 1536, 512, 12,
                                                     projw, wp, 256,
                                                     fc1w, w1, 1024, REP);
    attn_kernel<<<512 + 1024, 256, 0, stream>>>(qkvb, relb, attb, fc2w, w2, REP);
    gemm32<1><<<dim3(64, 8), 256, 0, stream>>>(attb, wp, projb, x, nullptr,
                                               nullptr, x2b, 4096, 512, 512, REP);
    ln_kernel_b<<<1024, 256, 0, stream>>>(x2b, n2w, n2b, hb, REP);
    gemm16<2><<<dim3(32, 16), 256, 0, stream>>>(hb, w1, fc1b, mb,
                                                4096, 2048, 512, 16,
                                                nullptr, nullptr, 0,
                                                nullptr, nullptr, 0, REP);
    gemm32<3><<<dim3(64, 8), 256, 0, stream>>>(mb, w2, fc2b, nullptr, x2b,
                                               out, nullptr, 4096, 512, 2048, REP);
}

// Round 8
// 196.412 us; speedup vs baseline: 2.1644x; 2.1644x over previous
//
#include <hip/hip_runtime.h>

typedef unsigned short u16;
typedef unsigned int uint;
typedef __attribute__((ext_vector_type(4))) float floatx4;
typedef __attribute__((ext_vector_type(16))) float floatx16;
typedef __attribute__((ext_vector_type(8))) short shortx8;

// ---------- helpers ----------
__device__ __forceinline__ u16 f2b(float f) {
    unsigned int u = __float_as_uint(f);
    unsigned int r = (u + 0x7fffu + ((u >> 16) & 1u)) >> 16;
    return (u16)r;
}
__device__ __forceinline__ float b2f(u16 u) {
    return __uint_as_float(((unsigned int)u) << 16);
}
__device__ __forceinline__ void gl_lds16(const u16* g, u16* l) {
    __builtin_amdgcn_global_load_lds(
        (const __attribute__((address_space(1))) void*)g,
        (__attribute__((address_space(3))) void*)l, 16, 0, 0);
}
__device__ __forceinline__ float gelu_f(float v) {
    float e = __expf(1.59576912f * v * (1.0f + 0.044715f * v * v));
    return v * e / (e + 1.0f);
}
// one 1024-f32 weight-cvt chunk (f32 -> bf16), 256 threads
__device__ __forceinline__ void cvt_block(const float* __restrict__ src,
                                          u16* __restrict__ dst, int i0) {
    int i = i0 * 256 + threadIdx.x;
    float4 v = ((const float4*)src)[i];
    uint2 o;
    o.x = (uint)f2b(v.x) | ((uint)f2b(v.y) << 16);
    o.y = (uint)f2b(v.z) | ((uint)f2b(v.w) << 16);
    ((uint2*)dst)[i] = o;
}

// ---------- wave-per-row LN (C=512): 8 elems/lane, shuffle-only ----------
__device__ __forceinline__ void ln_row_wave_f32(const float* __restrict__ x,
                                                const float* __restrict__ w,
                                                const float* __restrict__ b,
                                                u16* __restrict__ out, int row) {
    int lane = threadIdx.x & 63;
    const float4* xr = (const float4*)(x + (size_t)row * 512);
    float4 v0 = xr[lane * 2], v1 = xr[lane * 2 + 1];
    float s = v0.x + v0.y + v0.z + v0.w + v1.x + v1.y + v1.z + v1.w;
    float s2 = v0.x * v0.x + v0.y * v0.y + v0.z * v0.z + v0.w * v0.w +
               v1.x * v1.x + v1.y * v1.y + v1.z * v1.z + v1.w * v1.w;
    #pragma unroll
    for (int o = 32; o > 0; o >>= 1) {
        s += __shfl_xor(s, o, 64);
        s2 += __shfl_xor(s2, o, 64);
    }
    float mu = s * (1.0f / 512.0f);
    float var = s2 * (1.0f / 512.0f) - mu * mu;
    float rstd = rsqrtf(var + 1e-5f);
    const float4* wr = (const float4*)w;
    const float4* br = (const float4*)b;
    float4 w0 = wr[lane * 2], w1 = wr[lane * 2 + 1];
    float4 b0 = br[lane * 2], b1 = br[lane * 2 + 1];
    uint4 o4;
    o4.x = (uint)f2b((v0.x - mu) * rstd * w0.x + b0.x) |
           ((uint)f2b((v0.y - mu) * rstd * w0.y + b0.y) << 16);
    o4.y = (uint)f2b((v0.z - mu) * rstd * w0.z + b0.z) |
           ((uint)f2b((v0.w - mu) * rstd * w0.w + b0.w) << 16);
    o4.z = (uint)f2b((v1.x - mu) * rstd * w1.x + b1.x) |
           ((uint)f2b((v1.y - mu) * rstd * w1.y + b1.y) << 16);
    o4.w = (uint)f2b((v1.z - mu) * rstd * w1.z + b1.z) |
           ((uint)f2b((v1.w - mu) * rstd * w1.w + b1.w) << 16);
    ((uint4*)(out + (size_t)row * 512))[lane] = o4;
}

__device__ __forceinline__ void ln_row_wave_b16(const u16* __restrict__ x,
                                                const float* __restrict__ w,
                                                const float* __restrict__ b,
                                                u16* __restrict__ out, int row) {
    int lane = threadIdx.x & 63;
    uint4 p = ((const uint4*)(x + (size_t)row * 512))[lane];
    float v[8];
    v[0] = b2f((u16)(p.x & 0xffffu)); v[1] = b2f((u16)(p.x >> 16));
    v[2] = b2f((u16)(p.y & 0xffffu)); v[3] = b2f((u16)(p.y >> 16));
    v[4] = b2f((u16)(p.z & 0xffffu)); v[5] = b2f((u16)(p.z >> 16));
    v[6] = b2f((u16)(p.w & 0xffffu)); v[7] = b2f((u16)(p.w >> 16));
    float s = 0.f, s2 = 0.f;
    #pragma unroll
    for (int i = 0; i < 8; i++) { s += v[i]; s2 += v[i] * v[i]; }
    #pragma unroll
    for (int o = 32; o > 0; o >>= 1) {
        s += __shfl_xor(s, o, 64);
        s2 += __shfl_xor(s2, o, 64);
    }
    float mu = s * (1.0f / 512.0f);
    float var = s2 * (1.0f / 512.0f) - mu * mu;
    float rstd = rsqrtf(var + 1e-5f);
    const float4* wr = (const float4*)w;
    const float4* br = (const float4*)b;
    float4 w0 = wr[lane * 2], w1 = wr[lane * 2 + 1];
    float4 b0 = br[lane * 2], b1 = br[lane * 2 + 1];
    float o8[8];
    o8[0] = (v[0] - mu) * rstd * w0.x + b0.x;
    o8[1] = (v[1] - mu) * rstd * w0.y + b0.y;
    o8[2] = (v[2] - mu) * rstd * w0.z + b0.z;
    o8[3] = (v[3] - mu) * rstd * w0.w + b0.w;
    o8[4] = (v[4] - mu) * rstd * w1.x + b1.x;
    o8[5] = (v[5] - mu) * rstd * w1.y + b1.y;
    o8[6] = (v[6] - mu) * rstd * w1.z + b1.z;
    o8[7] = (v[7] - mu) * rstd * w1.w + b1.w;
    uint4 o4;
    o4.x = (uint)f2b(o8[0]) | ((uint)f2b(o8[1]) << 16);
    o4.y = (uint)f2b(o8[2]) | ((uint)f2b(o8[3]) << 16);
    o4.z = (uint)f2b(o8[4]) | ((uint)f2b(o8[5]) << 16);
    o4.w = (uint)f2b(o8[6]) | ((uint)f2b(o8[7]) << 16);
    ((uint4*)(out + (size_t)row * 512))[lane] = o4;
}

// ---------- GEMM A: 16x16x32 MFMA, MI=NI=4 frag reuse, dbuf, 128x128 BK=64 ----
// EPI: 0 bias->bf16 | 2 bias+GELU->bf16
// PRO (R7 lesson: boundaries cost ~15us each; fuse LN/cvt via redundant
// same-block recompute — each block writes ONLY rows/panels it later reads,
// so visibility is own-L2 RAW through __syncthreads' vmcnt drain):
//   0: none
//   1: LN(f32 lnx)->lnout for own 128 A-rows (x12 redundant) + cvt own
//      128-row W-panel f32->bf16 (x32 redundant, identical stores)
//   2: LN(bf16 lnx)->lnout for own 128 A-rows (x16 redundant)
template <int EPI, int PRO>
__global__ __launch_bounds__(256, 2) void gemm16(const u16* __restrict__ A,
                                                 const u16* __restrict__ W,
                                                 const float* __restrict__ bias,
                                                 u16* __restrict__ outB,
                                                 int M, int Nn, int K, int nby,
                                                 const float* __restrict__ cs0,
                                                 u16* __restrict__ cd0, int cn0,
                                                 const float* __restrict__ cs1,
                                                 u16* __restrict__ cd1, int cn1,
                                                 const void* __restrict__ lnx,
                                                 const float* __restrict__ lnw,
                                                 const float* __restrict__ lnb,
                                                 u16* __restrict__ lnout,
                                                 const float* __restrict__ wsrc,
                                                 u16* __restrict__ wdst) {
    constexpr int BM = 128, BN = 128, BK = 64;
    __shared__ u16 a_s[2][BM * BK];
    __shared__ u16 b_s[2][BN * BK];

    if ((int)blockIdx.y >= nby) {         // weight-cvt tail blocks
        int flat = ((int)blockIdx.y - nby) * (int)gridDim.x + (int)blockIdx.x;
        if (flat < cn0)            cvt_block(cs0, cd0, flat);
        else if (flat < cn0 + cn1) cvt_block(cs1, cd1, flat - cn0);
        return;
    }

    int tid = threadIdx.x;
    int wid = tid >> 6, lane = tid & 63;
    int wm = wid >> 1, wn = wid & 1;
    int m_blk = blockIdx.x * BM;
    int n_blk = blockIdx.y * BN;
    int lr = lane & 15;
    int lkc = lane >> 4;

    if (PRO != 0) {
        // LN own A-rows: 4 waves x 32 rows; unroll for load pipelining
        #pragma unroll 4
        for (int i = 0; i < 32; ++i) {
            int row = m_blk + wid * 32 + i;
            if (PRO == 1)
                ln_row_wave_f32((const float*)lnx, lnw, lnb, lnout, row);
            else
                ln_row_wave_b16((const u16*)lnx, lnw, lnb, lnout, row);
        }
        if (PRO == 1) {
            // cvt own W-panel: rows n_blk..+127, K f32 each = K/8 chunks of 1024
            int base = blockIdx.y * (BN * 512 / 1024);   // K==512 here
            #pragma unroll 4
            for (int c = 0; c < BN * 512 / 1024; ++c)
                cvt_block(wsrc, wdst, base + c);
        }
        __syncthreads();   // drains vmcnt: own stores in L2 before gl_lds16
    }

    floatx4 acc[4][4];
    #pragma unroll
    for (int i = 0; i < 4; i++)
        #pragma unroll
        for (int j = 0; j < 4; j++) acc[i][j] = (floatx4){0.f, 0.f, 0.f, 0.f};

    const u16* Ag = A + (size_t)m_blk * K;
    const u16* Wg = W + (size_t)n_blk * K;

    int srow = tid >> 3;
    int skc = (tid & 7) ^ (srow & 7);

    auto stage = [&](int k0, int buf) {
        #pragma unroll
        for (int p = 0; p < 4; p++)
            gl_lds16(Ag + (size_t)(p * 32 + srow) * K + k0 + skc * 8,
                     a_s[buf] + (p * 256 + tid) * 8);
        #pragma unroll
        for (int p = 0; p < 4; p++)
            gl_lds16(Wg + (size_t)(p * 32 + srow) * K + k0 + skc * 8,
                     b_s[buf] + (p * 256 + tid) * 8);
    };

    stage(0, 0);
    int nit = K >> 6;
    for (int it = 0; it < nit; it++) {
        __syncthreads();
        if (it + 1 < nit) stage((it + 1) << 6, (it + 1) & 1);
        int cb = it & 1;
        #pragma unroll
        for (int s = 0; s < 2; s++) {
            int kc = s * 4 + lkc;
            shortx8 af[4], bf[4];
            #pragma unroll
            for (int i = 0; i < 4; i++) {
                int row = wm * 64 + i * 16 + lr;
                af[i] = *(const shortx8*)(a_s[cb] + (row * 8 + (kc ^ (row & 7))) * 8);
            }
            #pragma unroll
            for (int j = 0; j < 4; j++) {
                int row = wn * 64 + j * 16 + lr;
                bf[j] = *(const shortx8*)(b_s[cb] + (row * 8 + (kc ^ (row & 7))) * 8);
            }
            #pragma unroll
            for (int i = 0; i < 4; i++)
                #pragma unroll
                for (int j = 0; j < 4; j++)
                    acc[i][j] = __builtin_amdgcn_mfma_f32_16x16x32_bf16(
                        af[i], bf[j], acc[i][j], 0, 0, 0);
        }
    }

    // C/D: col = lane&15, row = (lane>>4)*4 + r
    int col_l = lane & 15;
    int row_base = (lane >> 4) * 4;
    #pragma unroll
    for (int nj = 0; nj < 4; nj++) {
        int col = n_blk + wn * 64 + nj * 16 + col_l;
        float bv = bias[col];
        #pragma unroll
        for (int mi = 0; mi < 4; mi++) {
            #pragma unroll
            for (int r = 0; r < 4; r++) {
                int row = m_blk + wm * 64 + mi * 16 + row_base + r;
                size_t off = (size_t)row * Nn + col;
                float v = acc[mi][nj][r] + bv;
                outB[off] = f2b(EPI == 2 ? gelu_f(v) : v);
            }
        }
    }
}

// ---------- GEMM B: 32x32x16, 64x64 block, BK=128, dbuf (N=512 GEMMs) ----------
// EPI: 1 bias+residF32->bf16 | 3 bias+residB16->fp32 (d_out)
template <int EPI>
__global__ __launch_bounds__(256, 2) void gemm32(const u16* __restrict__ A,
                                                 const u16* __restrict__ W,
                                                 const float* __restrict__ bias,
                                                 const float* __restrict__ residF,
                                                 const u16* __restrict__ residB,
                                                 float* __restrict__ outF,
                                                 u16* __restrict__ outB,
                                                 int M, int Nn, int K) {
    constexpr int BM = 64, BN = 64, BK = 128;
    constexpr int CPR = BK / 8, KMSK = CPR - 1;
    __shared__ u16 a_s[2][BM * BK];
    __shared__ u16 b_s[2][BN * BK];

    int tid = threadIdx.x;
    int wid = tid >> 6, lane = tid & 63;
    int wm = wid >> 1, wn = wid & 1;
    int m_blk = blockIdx.x * BM;
    int n_blk = blockIdx.y * BN;
    int lr = lane & 31;
    int lk = lane >> 5;

    floatx16 acc;
    #pragma unroll
    for (int r = 0; r < 16; r++) acc[r] = 0.f;

    const u16* Ag = A + (size_t)m_blk * K;
    const u16* Wg = W + (size_t)n_blk * K;

    int srow = tid / CPR;
    int skc = (tid & KMSK) ^ (srow & KMSK);

    auto stage = [&](int k0, int buf) {
        #pragma unroll
        for (int p = 0; p < 4; p++)
            gl_lds16(Ag + (size_t)(p * 16 + srow) * K + k0 + skc * 8,
                     a_s[buf] + (p * 256 + tid) * 8);
        #pragma unroll
        for (int p = 0; p < 4; p++)
            gl_lds16(Wg + (size_t)(p * 16 + srow) * K + k0 + skc * 8,
                     b_s[buf] + (p * 256 + tid) * 8);
    };

    stage(0, 0);
    int nit = K / BK;
    for (int it = 0; it < nit; it++) {
        __syncthreads();
        if (it + 1 < nit) stage((it + 1) * BK, (it + 1) & 1);
        int cb = it & 1;
        #pragma unroll
        for (int s = 0; s < BK / 16; s++) {
            int kc = s * 2 + lk;
            int arow = wm * 32 + lr;
            int brow = wn * 32 + lr;
            shortx8 af = *(const shortx8*)(a_s[cb] + (arow * CPR + (kc ^ (arow & KMSK))) * 8);
            shortx8 bf = *(const shortx8*)(b_s[cb] + (brow * CPR + (kc ^ (brow & KMSK))) * 8);
            acc = __builtin_amdgcn_mfma_f32_32x32x16_bf16(af, bf, acc, 0, 0, 0);
        }
    }

    int col_l = lane & 31;
    int row_q = 4 * (lane >> 5);
    int col = n_blk + wn * 32 + col_l;
    float bv = bias[col];
    #pragma unroll
    for (int r = 0; r < 16; r++) {
        int row = m_blk + wm * 32 + (r & 3) + 8 * (r >> 2) + row_q;
        size_t off = (size_t)row * Nn + col;
        float v = acc[r] + bv;
        if (EPI == 1) outB[off] = f2b(v + residF[off]);
        else          outF[off] = v + b2f(residB[off]);
    }
}

// ---------- windowed attention, MFMA flash-style ----------
__global__ __launch_bounds__(256) void attn_kernel(const u16* __restrict__ qkv,
                                                   const float* __restrict__ rel_bias,
                                                   u16* __restrict__ out,
                                                   const float* __restrict__ csrc,
                                                   u16* __restrict__ cdst) {
    __shared__ u16 k_s[128][76];
    __shared__ u16 v_t[64][154];
    __shared__ u16 p_s[4][16][106];
    __shared__ float s_bias[64];

    int bx = blockIdx.x;
    if (bx >= 512) {                      // weight-cvt tail (w2)
        cvt_block(csrc, cdst, bx - 512);
        return;
    }
    int n = bx >> 8;
    int h = (bx >> 5) & 7;
    int t0 = (bx & 31) << 6;
    int tid = threadIdx.x, wid = tid >> 6, lane = tid & 63;
    int col = lane & 15, rq = lane >> 4;

    const u16* qrow = qkv + (size_t)(n * 2048 + t0 + wid * 16 + col) * 1536 + h * 64 + rq * 8;
    shortx8 qf0 = *(const shortx8*)qrow;
    shortx8 qf1 = *(const shortx8*)(qrow + 32);

    if (tid < 63) s_bias[tid] = rel_bias[h * 63 + tid];
    if (tid == 63) s_bias[63] = 0.f;

    const uint* qkv_u = (const uint*)qkv;
    for (int idx = tid; idx < 128 * 16; idx += 256) {
        int row = idx >> 4, j2 = idx & 15;
        int pos = t0 - 31 + row;
        uint2 kv; kv.x = 0u; kv.y = 0u;
        if (pos >= 0 && pos < 2048)
            kv = *(const uint2*)(qkv_u + (size_t)(n * 2048 + pos) * 768 + 256 + h * 32 + j2 * 2);
        *(uint2*)&k_s[row][j2 * 4] = kv;
    }
    for (int idx = tid; idx < 72 * 32; idx += 256) {
        int rp = idx >> 5, j = idx & 31;
        int r0 = rp * 2;
        int p0 = t0 - 31 + r0, p1 = p0 + 1;
        uint a = 0u, b = 0u;
        if (p0 >= 0 && p0 < 2048)
            a = qkv_u[(size_t)(n * 2048 + p0) * 768 + 512 + h * 32 + j];
        if (p1 >= 0 && p1 < 2048)
            b = qkv_u[(size_t)(n * 2048 + p1) * 768 + 512 + h * 32 + j];
        *(uint*)&v_t[2 * j][r0]     = (a & 0xffffu) | (b << 16);
        *(uint*)&v_t[2 * j + 1][r0] = (a >> 16) | (b & 0xffff0000u);
    }
    __syncthreads();

    floatx4 S[5];
    #pragma unroll
    for (int nt = 0; nt < 5; nt++) S[nt] = (floatx4){0.f, 0.f, 0.f, 0.f};
    #pragma unroll
    for (int nt = 0; nt < 5; nt++) {
        const u16* kb = &k_s[wid * 16 + nt * 16 + col][rq * 8];
        shortx8 b0 = *(const shortx8*)kb;
        shortx8 b1 = *(const shortx8*)(kb + 32);
        S[nt] = __builtin_amdgcn_mfma_f32_16x16x32_bf16(qf0, b0, S[nt], 0, 0, 0);
        S[nt] = __builtin_amdgcn_mfma_f32_16x16x32_bf16(qf1, b1, S[nt], 0, 0, 0);
    }

    #pragma unroll
    for (int r = 0; r < 4; r++) {
        int t_row = rq * 4 + r;
        float sc[5];
        float mx = -1e30f;
        #pragma unroll
        for (int nt = 0; nt < 5; nt++) {
            int w = nt * 16 + col - t_row;
            int pos_abs = t0 - 31 + wid * 16 + nt * 16 + col;
            float v;
            if (w < 0 || w > 62) {
                v = -1e30f;
            } else {
                v = S[nt][r] * 0.125f + s_bias[w];
                if (pos_abs < 0 || pos_abs >= 2048) v -= 100.f;
            }
            sc[nt] = v;
            mx = fmaxf(mx, v);
        }
        #pragma unroll
        for (int o = 1; o < 16; o <<= 1) mx = fmaxf(mx, __shfl_xor(mx, o, 64));
        float l = 0.f;
        #pragma unroll
        for (int nt = 0; nt < 5; nt++) {
            sc[nt] = __expf(sc[nt] - mx);
            l += sc[nt];
        }
        #pragma unroll
        for (int o = 1; o < 16; o <<= 1) l += __shfl_xor(l, o, 64);
        float inv = 1.0f / l;
        #pragma unroll
        for (int nt = 0; nt < 5; nt++)
            p_s[wid][t_row][nt * 16 + col] = f2b(sc[nt] * inv);
        p_s[wid][t_row][80 + col] = 0;
    }
    __syncthreads();

    floatx4 O[4];
    #pragma unroll
    for (int dt = 0; dt < 4; dt++) O[dt] = (floatx4){0.f, 0.f, 0.f, 0.f};
    const u16* pr = &p_s[wid][col][rq * 8];
    shortx8 a0 = *(const shortx8*)pr;
    shortx8 a1 = *(const shortx8*)(pr + 32);
    shortx8 a2 = *(const shortx8*)(pr + 64);
    #pragma unroll
    for (int dt = 0; dt < 4; dt++) {
        const u16* vb = &v_t[dt * 16 + col][wid * 16 + rq * 8];
        shortx8 b0 = *(const shortx8*)vb;
        shortx8 b1 = *(const shortx8*)(vb + 32);
        shortx8 b2 = *(const shortx8*)(vb + 64);
        O[dt] = __builtin_amdgcn_mfma_f32_16x16x32_bf16(a0, b0, O[dt], 0, 0, 0);
        O[dt] = __builtin_amdgcn_mfma_f32_16x16x32_bf16(a1, b1, O[dt], 0, 0, 0);
        O[dt] = __builtin_amdgcn_mfma_f32_16x16x32_bf16(a2, b2, O[dt], 0, 0, 0);
    }

    #pragma unroll
    for (int dt = 0; dt < 4; dt++) {
        #pragma unroll
        for (int r = 0; r < 4; r++) {
            int t_row = rq * 4 + r;
            out[(size_t)(n * 2048 + t0 + wid * 16 + t_row) * 512 + h * 64 + dt * 16 + col] =
                f2b(O[dt][r]);
        }
    }
}

// ---------- launcher: 5 kernels (was 7; prep + LN2 fused into the GEMMs) ----
extern "C" void kernel_launch(void* const* d_in, const int* in_sizes, int n_in,
                              void* d_out, int out_size, void* d_ws, size_t ws_size,
                              hipStream_t stream) {
    const float* x     = (const float*)d_in[0];
    const float* n1w   = (const float*)d_in[1];
    const float* n1b   = (const float*)d_in[2];
    const float* qkvw  = (const float*)d_in[3];
    const float* qkvbv = (const float*)d_in[4];
    const float* relb  = (const float*)d_in[5];
    const float* projw = (const float*)d_in[6];
    const float* projb = (const float*)d_in[7];
    const float* n2w   = (const float*)d_in[8];
    const float* n2b   = (const float*)d_in[9];
    const float* fc1w  = (const float*)d_in[10];
    const float* fc1b  = (const float*)d_in[11];
    const float* fc2w  = (const float*)d_in[12];
    const float* fc2b  = (const float*)d_in[13];
    float* out = (float*)d_out;

    char* p = (char*)d_ws;
    u16* wq   = (u16*)p;  p += (size_t)786432 * 2;   // qkv_w bf16 (1536x512)
    u16* wp   = (u16*)p;  p += (size_t)262144 * 2;   // proj_w bf16 (512x512)
    u16* w1   = (u16*)p;  p += (size_t)1048576 * 2;  // fc1_w bf16 (2048x512)
    u16* w2   = (u16*)p;  p += (size_t)1048576 * 2;  // fc2_w bf16 (512x2048)
    u16* hb1  = (u16*)p;  p += (size_t)2097152 * 2;  // LN1 out bf16 (4096x512)
    u16* hb2  = (u16*)p;  p += (size_t)2097152 * 2;  // LN2 out bf16 (4096x512)
    u16* qkvb = (u16*)p;  p += (size_t)6291456 * 2;  // qkv bf16 (4096x1536)
    u16* attb = (u16*)p;  p += (size_t)2097152 * 2;  // attn out bf16 (4096x512)
    u16* x2b  = (u16*)p;  p += (size_t)2097152 * 2;  // x + proj(attn), bf16
    u16* mb   = (u16*)p;  p += (size_t)8388608 * 2;  // gelu(fc1) bf16 (4096x2048)

    // 1) qkv GEMM + in-block LN1(x->hb1) + in-block wq cvt + wp/w1 cvt tails
    gemm16<0, 1><<<dim3(32, 12 + 40), 256, 0, stream>>>(
        hb1, wq, qkvbv, qkvb, 4096, 1536, 512, 12,
        projw, wp, 256, fc1w, w1, 1024,
        x, n1w, n1b, hb1, qkvw, wq);
    // 2) attention + w2 cvt tail
    attn_kernel<<<512 + 1024, 256, 0, stream>>>(qkvb, relb, attb, fc2w, w2);
    // 3) proj: x2 = x + attb @ wp^T + b (bf16)
    gemm32<1><<<dim3(64, 8), 256, 0, stream>>>(attb, wp, projb, x, nullptr,
                                               nullptr, x2b, 4096, 512, 512);
    // 4) fc1 + GELU + in-block LN2(x2b->hb2)
    gemm16<2, 2><<<dim3(32, 16), 256, 0, stream>>>(
        hb2, w1, fc1b, mb, 4096, 2048, 512, 16,
        nullptr, nullptr, 0, nullptr, nullptr, 0,
        x2b, n2w, n2b, hb2, nullptr, nullptr);
    // 5) fc2: out = x2 + mb @ w2^T + b (fp32)
    gemm32<3><<<dim3(64, 8), 256, 0, stream>>>(mb, w2, fc2b, nullptr, x2b,
                                               out, nullptr, 4096, 512, 2048);
}

// Round 10
// 177.738 us; speedup vs baseline: 2.3918x; 1.1051x over previous
//
#include <hip/hip_runtime.h>

typedef unsigned short u16;
typedef unsigned int uint;
typedef __attribute__((ext_vector_type(4))) float floatx4;
typedef __attribute__((ext_vector_type(16))) float floatx16;
typedef __attribute__((ext_vector_type(8))) short shortx8;

// ---------- helpers ----------
__device__ __forceinline__ u16 f2b(float f) {
    unsigned int u = __float_as_uint(f);
    unsigned int r = (u + 0x7fffu + ((u >> 16) & 1u)) >> 16;
    return (u16)r;
}
__device__ __forceinline__ float b2f(u16 u) {
    return __uint_as_float(((unsigned int)u) << 16);
}
__device__ __forceinline__ void gl_lds16(const u16* g, u16* l) {
    __builtin_amdgcn_global_load_lds(
        (const __attribute__((address_space(1))) void*)g,
        (__attribute__((address_space(3))) void*)l, 16, 0, 0);
}
__device__ __forceinline__ float gelu_f(float v) {
    float e = __expf(1.59576912f * v * (1.0f + 0.044715f * v * v));
    return v * e / (e + 1.0f);
}
// one 1024-f32 weight-cvt chunk (f32 -> bf16), 256 threads
__device__ __forceinline__ void cvt_block(const float* __restrict__ src,
                                          u16* __restrict__ dst, int i0) {
    int i = i0 * 256 + threadIdx.x;
    float4 v = ((const float4*)src)[i];
    uint2 o;
    o.x = (uint)f2b(v.x) | ((uint)f2b(v.y) << 16);
    o.y = (uint)f2b(v.z) | ((uint)f2b(v.w) << 16);
    ((uint2*)dst)[i] = o;
}

// ---------- wave-per-row LN (C=512): 8 elems/lane, shuffle-only ----------
__device__ __forceinline__ void ln_row_wave_f32(const float* __restrict__ x,
                                                const float* __restrict__ w,
                                                const float* __restrict__ b,
                                                u16* __restrict__ out, int row) {
    int lane = threadIdx.x & 63;
    const float4* xr = (const float4*)(x + (size_t)row * 512);
    float4 v0 = xr[lane * 2], v1 = xr[lane * 2 + 1];
    float s = v0.x + v0.y + v0.z + v0.w + v1.x + v1.y + v1.z + v1.w;
    float s2 = v0.x * v0.x + v0.y * v0.y + v0.z * v0.z + v0.w * v0.w +
               v1.x * v1.x + v1.y * v1.y + v1.z * v1.z + v1.w * v1.w;
    #pragma unroll
    for (int o = 32; o > 0; o >>= 1) {
        s += __shfl_xor(s, o, 64);
        s2 += __shfl_xor(s2, o, 64);
    }
    float mu = s * (1.0f / 512.0f);
    float var = s2 * (1.0f / 512.0f) - mu * mu;
    float rstd = rsqrtf(var + 1e-5f);
    const float4* wr = (const float4*)w;
    const float4* br = (const float4*)b;
    float4 w0 = wr[lane * 2], w1 = wr[lane * 2 + 1];
    float4 b0 = br[lane * 2], b1 = br[lane * 2 + 1];
    uint4 o4;
    o4.x = (uint)f2b((v0.x - mu) * rstd * w0.x + b0.x) |
           ((uint)f2b((v0.y - mu) * rstd * w0.y + b0.y) << 16);
    o4.y = (uint)f2b((v0.z - mu) * rstd * w0.z + b0.z) |
           ((uint)f2b((v0.w - mu) * rstd * w0.w + b0.w) << 16);
    o4.z = (uint)f2b((v1.x - mu) * rstd * w1.x + b1.x) |
           ((uint)f2b((v1.y - mu) * rstd * w1.y + b1.y) << 16);
    o4.w = (uint)f2b((v1.z - mu) * rstd * w1.z + b1.z) |
           ((uint)f2b((v1.w - mu) * rstd * w1.w + b1.w) << 16);
    ((uint4*)(out + (size_t)row * 512))[lane] = o4;
}

__device__ __forceinline__ void ln_row_wave_b16(const u16* __restrict__ x,
                                                const float* __restrict__ w,
                                                const float* __restrict__ b,
                                                u16* __restrict__ out, int row) {
    int lane = threadIdx.x & 63;
    uint4 p = ((const uint4*)(x + (size_t)row * 512))[lane];
    float v[8];
    v[0] = b2f((u16)(p.x & 0xffffu)); v[1] = b2f((u16)(p.x >> 16));
    v[2] = b2f((u16)(p.y & 0xffffu)); v[3] = b2f((u16)(p.y >> 16));
    v[4] = b2f((u16)(p.z & 0xffffu)); v[5] = b2f((u16)(p.z >> 16));
    v[6] = b2f((u16)(p.w & 0xffffu)); v[7] = b2f((u16)(p.w >> 16));
    float s = 0.f, s2 = 0.f;
    #pragma unroll
    for (int i = 0; i < 8; i++) { s += v[i]; s2 += v[i] * v[i]; }
    #pragma unroll
    for (int o = 32; o > 0; o >>= 1) {
        s += __shfl_xor(s, o, 64);
        s2 += __shfl_xor(s2, o, 64);
    }
    float mu = s * (1.0f / 512.0f);
    float var = s2 * (1.0f / 512.0f) - mu * mu;
    float rstd = rsqrtf(var + 1e-5f);
    const float4* wr = (const float4*)w;
    const float4* br = (const float4*)b;
    float4 w0 = wr[lane * 2], w1 = wr[lane * 2 + 1];
    float4 b0 = br[lane * 2], b1 = br[lane * 2 + 1];
    float o8[8];
    o8[0] = (v[0] - mu) * rstd * w0.x + b0.x;
    o8[1] = (v[1] - mu) * rstd * w0.y + b0.y;
    o8[2] = (v[2] - mu) * rstd * w0.z + b0.z;
    o8[3] = (v[3] - mu) * rstd * w0.w + b0.w;
    o8[4] = (v[4] - mu) * rstd * w1.x + b1.x;
    o8[5] = (v[5] - mu) * rstd * w1.y + b1.y;
    o8[6] = (v[6] - mu) * rstd * w1.z + b1.z;
    o8[7] = (v[7] - mu) * rstd * w1.w + b1.w;
    uint4 o4;
    o4.x = (uint)f2b(o8[0]) | ((uint)f2b(o8[1]) << 16);
    o4.y = (uint)f2b(o8[2]) | ((uint)f2b(o8[3]) << 16);
    o4.z = (uint)f2b(o8[4]) | ((uint)f2b(o8[5]) << 16);
    o4.w = (uint)f2b(o8[6]) | ((uint)f2b(o8[7]) << 16);
    ((uint4*)(out + (size_t)row * 512))[lane] = o4;
}

// ---------- prep: cvt wq + LN1 (R8 lesson: LN1 fusion re-reads f32 x from
// HBM x12 after L3 eviction by inter-iteration fills -> keep standalone) ----
__global__ __launch_bounds__(256) void prep_kernel(
    const float* __restrict__ qkvw, u16* __restrict__ wq,
    const float* __restrict__ x, const float* __restrict__ n1w,
    const float* __restrict__ n1b, u16* __restrict__ hb) {
    int bi = blockIdx.x;
    if (bi < 768) {
        cvt_block(qkvw, wq, bi);
    } else {
        int row = (bi - 768) * 4 + (threadIdx.x >> 6);
        ln_row_wave_f32(x, n1w, n1b, hb, row);
    }
}

// ---------- GEMM A: 16x16x32 MFMA, MI=NI=4 frag reuse, dbuf, 128x128 BK=64 ----
// EPI: 0 bias->bf16 | 2 bias+GELU->bf16
// PRO=2: fused LN2 prologue — each block LNs its OWN 128 A-rows from bf16
// lnx (x16 redundant across n-blocks, but lnx is a same-iteration 4MB bf16
// intermediate => L2/L3-priced, ~2-4us total; removes a ~12us launch).
// Own-block RAW: full rows written -> own-L2 dirty lines -> gl_lds16 hits.
template <int EPI, int PRO>
__global__ __launch_bounds__(256, 2) void gemm16(const u16* __restrict__ A,
                                                 const u16* __restrict__ W,
                                                 const float* __restrict__ bias,
                                                 u16* __restrict__ outB,
                                                 int M, int Nn, int K, int nby,
                                                 const float* __restrict__ cs0,
                                                 u16* __restrict__ cd0, int cn0,
                                                 const float* __restrict__ cs1,
                                                 u16* __restrict__ cd1, int cn1,
                                                 const u16* __restrict__ lnx,
                                                 const float* __restrict__ lnw,
                                                 const float* __restrict__ lnb,
                                                 u16* __restrict__ lnout) {
    constexpr int BM = 128, BN = 128, BK = 64;
    __shared__ u16 a_s[2][BM * BK];
    __shared__ u16 b_s[2][BN * BK];

    if ((int)blockIdx.y >= nby) {         // weight-cvt tail blocks
        int flat = ((int)blockIdx.y - nby) * (int)gridDim.x + (int)blockIdx.x;
        if (flat < cn0)            cvt_block(cs0, cd0, flat);
        else if (flat < cn0 + cn1) cvt_block(cs1, cd1, flat - cn0);
        return;
    }

    int tid = threadIdx.x;
    int wid = tid >> 6, lane = tid & 63;
    int wm = wid >> 1, wn = wid & 1;
    int m_blk = blockIdx.x * BM;
    int n_blk = blockIdx.y * BN;
    int lr = lane & 15;
    int lkc = lane >> 4;

    if (PRO == 2) {
        #pragma unroll 4
        for (int i = 0; i < 32; ++i)
            ln_row_wave_b16(lnx, lnw, lnb, lnout, m_blk + wid * 32 + i);
        __syncthreads();   // drains vmcnt: own LN stores in L2 before gl_lds16
    }

    floatx4 acc[4][4];
    #pragma unroll
    for (int i = 0; i < 4; i++)
        #pragma unroll
        for (int j = 0; j < 4; j++) acc[i][j] = (floatx4){0.f, 0.f, 0.f, 0.f};

    const u16* Ag = A + (size_t)m_blk * K;
    const u16* Wg = W + (size_t)n_blk * K;

    int srow = tid >> 3;
    int skc = (tid & 7) ^ (srow & 7);

    auto stage = [&](int k0, int buf) {
        #pragma unroll
        for (int p = 0; p < 4; p++)
            gl_lds16(Ag + (size_t)(p * 32 + srow) * K + k0 + skc * 8,
                     a_s[buf] + (p * 256 + tid) * 8);
        #pragma unroll
        for (int p = 0; p < 4; p++)
            gl_lds16(Wg + (size_t)(p * 32 + srow) * K + k0 + skc * 8,
                     b_s[buf] + (p * 256 + tid) * 8);
    };

    stage(0, 0);
    int nit = K >> 6;
    for (int it = 0; it < nit; it++) {
        __syncthreads();
        if (it + 1 < nit) stage((it + 1) << 6, (it + 1) & 1);
        int cb = it & 1;
        #pragma unroll
        for (int s = 0; s < 2; s++) {
            int kc = s * 4 + lkc;
            shortx8 af[4], bf[4];
            #pragma unroll
            for (int i = 0; i < 4; i++) {
                int row = wm * 64 + i * 16 + lr;
                af[i] = *(const shortx8*)(a_s[cb] + (row * 8 + (kc ^ (row & 7))) * 8);
            }
            #pragma unroll
            for (int j = 0; j < 4; j++) {
                int row = wn * 64 + j * 16 + lr;
                bf[j] = *(const shortx8*)(b_s[cb] + (row * 8 + (kc ^ (row & 7))) * 8);
            }
            #pragma unroll
            for (int i = 0; i < 4; i++)
                #pragma unroll
                for (int j = 0; j < 4; j++)
                    acc[i][j] = __builtin_amdgcn_mfma_f32_16x16x32_bf16(
                        af[i], bf[j], acc[i][j], 0, 0, 0);
        }
    }

    // C/D: col = lane&15, row = (lane>>4)*4 + r
    int col_l = lane & 15;
    int row_base = (lane >> 4) * 4;
    #pragma unroll
    for (int nj = 0; nj < 4; nj++) {
        int col = n_blk + wn * 64 + nj * 16 + col_l;
        float bv = bias[col];
        #pragma unroll
        for (int mi = 0; mi < 4; mi++) {
            #pragma unroll
            for (int r = 0; r < 4; r++) {
                int row = m_blk + wm * 64 + mi * 16 + row_base + r;
                size_t off = (size_t)row * Nn + col;
                float v = acc[mi][nj][r] + bv;
                outB[off] = f2b(EPI == 2 ? gelu_f(v) : v);
            }
        }
    }
}

// ---------- GEMM B: 32x32x16, 64x64 block, BK=128, dbuf (N=512 GEMMs) ----------
// EPI: 1 bias+residF32->bf16 | 3 bias+residB16->fp32 (d_out)
template <int EPI>
__global__ __launch_bounds__(256, 2) void gemm32(const u16* __restrict__ A,
                                                 const u16* __restrict__ W,
                                                 const float* __restrict__ bias,
                                                 const float* __restrict__ residF,
                                                 const u16* __restrict__ residB,
                                                 float* __restrict__ outF,
                                                 u16* __restrict__ outB,
                                                 int M, int Nn, int K) {
    constexpr int BM = 64, BN = 64, BK = 128;
    constexpr int CPR = BK / 8, KMSK = CPR - 1;
    __shared__ u16 a_s[2][BM * BK];
    __shared__ u16 b_s[2][BN * BK];

    int tid = threadIdx.x;
    int wid = tid >> 6, lane = tid & 63;
    int wm = wid >> 1, wn = wid & 1;
    int m_blk = blockIdx.x * BM;
    int n_blk = blockIdx.y * BN;
    int lr = lane & 31;
    int lk = lane >> 5;

    floatx16 acc;
    #pragma unroll
    for (int r = 0; r < 16; r++) acc[r] = 0.f;

    const u16* Ag = A + (size_t)m_blk * K;
    const u16* Wg = W + (size_t)n_blk * K;

    int srow = tid / CPR;
    int skc = (tid & KMSK) ^ (srow & KMSK);

    auto stage = [&](int k0, int buf) {
        #pragma unroll
        for (int p = 0; p < 4; p++)
            gl_lds16(Ag + (size_t)(p * 16 + srow) * K + k0 + skc * 8,
                     a_s[buf] + (p * 256 + tid) * 8);
        #pragma unroll
        for (int p = 0; p < 4; p++)
            gl_lds16(Wg + (size_t)(p * 16 + srow) * K + k0 + skc * 8,
                     b_s[buf] + (p * 256 + tid) * 8);
    };

    stage(0, 0);
    int nit = K / BK;
    for (int it = 0; it < nit; it++) {
        __syncthreads();
        if (it + 1 < nit) stage((it + 1) * BK, (it + 1) & 1);
        int cb = it & 1;
        #pragma unroll
        for (int s = 0; s < BK / 16; s++) {
            int kc = s * 2 + lk;
            int arow = wm * 32 + lr;
            int brow = wn * 32 + lr;
            shortx8 af = *(const shortx8*)(a_s[cb] + (arow * CPR + (kc ^ (arow & KMSK))) * 8);
            shortx8 bf = *(const shortx8*)(b_s[cb] + (brow * CPR + (kc ^ (brow & KMSK))) * 8);
            acc = __builtin_amdgcn_mfma_f32_32x32x16_bf16(af, bf, acc, 0, 0, 0);
        }
    }

    int col_l = lane & 31;
    int row_q = 4 * (lane >> 5);
    int col = n_blk + wn * 32 + col_l;
    float bv = bias[col];
    #pragma unroll
    for (int r = 0; r < 16; r++) {
        int row = m_blk + wm * 32 + (r & 3) + 8 * (r >> 2) + row_q;
        size_t off = (size_t)row * Nn + col;
        float v = acc[r] + bv;
        if (EPI == 1) outB[off] = f2b(v + residF[off]);
        else          outF[off] = v + b2f(residB[off]);
    }
}

// ---------- windowed attention, MFMA flash-style ----------
__global__ __launch_bounds__(256) void attn_kernel(const u16* __restrict__ qkv,
                                                   const float* __restrict__ rel_bias,
                                                   u16* __restrict__ out,
                                                   const float* __restrict__ csrc,
                                                   u16* __restrict__ cdst) {
    __shared__ u16 k_s[128][76];
    __shared__ u16 v_t[64][154];
    __shared__ u16 p_s[4][16][106];
    __shared__ float s_bias[64];

    int bx = blockIdx.x;
    if (bx >= 512) {                      // weight-cvt tail (w2)
        cvt_block(csrc, cdst, bx - 512);
        return;
    }
    int n = bx >> 8;
    int h = (bx >> 5) & 7;
    int t0 = (bx & 31) << 6;
    int tid = threadIdx.x, wid = tid >> 6, lane = tid & 63;
    int col = lane & 15, rq = lane >> 4;

    const u16* qrow = qkv + (size_t)(n * 2048 + t0 + wid * 16 + col) * 1536 + h * 64 + rq * 8;
    shortx8 qf0 = *(const shortx8*)qrow;
    shortx8 qf1 = *(const shortx8*)(qrow + 32);

    if (tid < 63) s_bias[tid] = rel_bias[h * 63 + tid];
    if (tid == 63) s_bias[63] = 0.f;

    const uint* qkv_u = (const uint*)qkv;
    for (int idx = tid; idx < 128 * 16; idx += 256) {
        int row = idx >> 4, j2 = idx & 15;
        int pos = t0 - 31 + row;
        uint2 kv; kv.x = 0u; kv.y = 0u;
        if (pos >= 0 && pos < 2048)
            kv = *(const uint2*)(qkv_u + (size_t)(n * 2048 + pos) * 768 + 256 + h * 32 + j2 * 2);
        *(uint2*)&k_s[row][j2 * 4] = kv;
    }
    for (int idx = tid; idx < 72 * 32; idx += 256) {
        int rp = idx >> 5, j = idx & 31;
        int r0 = rp * 2;
        int p0 = t0 - 31 + r0, p1 = p0 + 1;
        uint a = 0u, b = 0u;
        if (p0 >= 0 && p0 < 2048)
            a = qkv_u[(size_t)(n * 2048 + p0) * 768 + 512 + h * 32 + j];
        if (p1 >= 0 && p1 < 2048)
            b = qkv_u[(size_t)(n * 2048 + p1) * 768 + 512 + h * 32 + j];
        *(uint*)&v_t[2 * j][r0]     = (a & 0xffffu) | (b << 16);
        *(uint*)&v_t[2 * j + 1][r0] = (a >> 16) | (b & 0xffff0000u);
    }
    __syncthreads();

    floatx4 S[5];
    #pragma unroll
    for (int nt = 0; nt < 5; nt++) S[nt] = (floatx4){0.f, 0.f, 0.f, 0.f};
    #pragma unroll
    for (int nt = 0; nt < 5; nt++) {
        const u16* kb = &k_s[wid * 16 + nt * 16 + col][rq * 8];
        shortx8 b0 = *(const shortx8*)kb;
        shortx8 b1 = *(const shortx8*)(kb + 32);
        S[nt] = __builtin_amdgcn_mfma_f32_16x16x32_bf16(qf0, b0, S[nt], 0, 0, 0);
        S[nt] = __builtin_amdgcn_mfma_f32_16x16x32_bf16(qf1, b1, S[nt], 0, 0, 0);
    }

    #pragma unroll
    for (int r = 0; r < 4; r++) {
        int t_row = rq * 4 + r;
        float sc[5];
        float mx = -1e30f;
        #pragma unroll
        for (int nt = 0; nt < 5; nt++) {
            int w = nt * 16 + col - t_row;
            int pos_abs = t0 - 31 + wid * 16 + nt * 16 + col;
            float v;
            if (w < 0 || w > 62) {
                v = -1e30f;
            } else {
                v = S[nt][r] * 0.125f + s_bias[w];
                if (pos_abs < 0 || pos_abs >= 2048) v -= 100.f;
            }
            sc[nt] = v;
            mx = fmaxf(mx, v);
        }
        #pragma unroll
        for (int o = 1; o < 16; o <<= 1) mx = fmaxf(mx, __shfl_xor(mx, o, 64));
        float l = 0.f;
        #pragma unroll
        for (int nt = 0; nt < 5; nt++) {
            sc[nt] = __expf(sc[nt] - mx);
            l += sc[nt];
        }
        #pragma unroll
        for (int o = 1; o < 16; o <<= 1) l += __shfl_xor(l, o, 64);
        float inv = 1.0f / l;
        #pragma unroll
        for (int nt = 0; nt < 5; nt++)
            p_s[wid][t_row][nt * 16 + col] = f2b(sc[nt] * inv);
        p_s[wid][t_row][80 + col] = 0;
    }
    __syncthreads();

    floatx4 O[4];
    #pragma unroll
    for (int dt = 0; dt < 4; dt++) O[dt] = (floatx4){0.f, 0.f, 0.f, 0.f};
    const u16* pr = &p_s[wid][col][rq * 8];
    shortx8 a0 = *(const shortx8*)pr;
    shortx8 a1 = *(const shortx8*)(pr + 32);
    shortx8 a2 = *(const shortx8*)(pr + 64);
    #pragma unroll
    for (int dt = 0; dt < 4; dt++) {
        const u16* vb = &v_t[dt * 16 + col][wid * 16 + rq * 8];
        shortx8 b0 = *(const shortx8*)vb;
        shortx8 b1 = *(const shortx8*)(vb + 32);
        shortx8 b2 = *(const shortx8*)(vb + 64);
        O[dt] = __builtin_amdgcn_mfma_f32_16x16x32_bf16(a0, b0, O[dt], 0, 0, 0);
        O[dt] = __builtin_amdgcn_mfma_f32_16x16x32_bf16(a1, b1, O[dt], 0, 0, 0);
        O[dt] = __builtin_amdgcn_mfma_f32_16x16x32_bf16(a2, b2, O[dt], 0, 0, 0);
    }

    #pragma unroll
    for (int dt = 0; dt < 4; dt++) {
        #pragma unroll
        for (int r = 0; r < 4; r++) {
            int t_row = rq * 4 + r;
            out[(size_t)(n * 2048 + t0 + wid * 16 + t_row) * 512 + h * 64 + dt * 16 + col] =
                f2b(O[dt][r]);
        }
    }
}

// ---------- launcher: 6 kernels (LN2 fused into fc1 prologue) ----------
extern "C" void kernel_launch(void* const* d_in, const int* in_sizes, int n_in,
                              void* d_out, int out_size, void* d_ws, size_t ws_size,
                              hipStream_t stream) {
    const float* x     = (const float*)d_in[0];
    const float* n1w   = (const float*)d_in[1];
    const float* n1b   = (const float*)d_in[2];
    const float* qkvw  = (const float*)d_in[3];
    const float* qkvbv = (const float*)d_in[4];
    const float* relb  = (const float*)d_in[5];
    const float* projw = (const float*)d_in[6];
    const float* projb = (const float*)d_in[7];
    const float* n2w   = (const float*)d_in[8];
    const float* n2b   = (const float*)d_in[9];
    const float* fc1w  = (const float*)d_in[10];
    const float* fc1b  = (const float*)d_in[11];
    const float* fc2w  = (const float*)d_in[12];
    const float* fc2b  = (const float*)d_in[13];
    float* out = (float*)d_out;

    char* p = (char*)d_ws;
    u16* wq   = (u16*)p;  p += (size_t)786432 * 2;   // qkv_w bf16 (1536x512)
    u16* wp   = (u16*)p;  p += (size_t)262144 * 2;   // proj_w bf16 (512x512)
    u16* w1   = (u16*)p;  p += (size_t)1048576 * 2;  // fc1_w bf16 (2048x512)
    u16* w2   = (u16*)p;  p += (size_t)1048576 * 2;  // fc2_w bf16 (512x2048)
    u16* hb1  = (u16*)p;  p += (size_t)2097152 * 2;  // LN1 out bf16 (4096x512)
    u16* hb2  = (u16*)p;  p += (size_t)2097152 * 2;  // LN2 out bf16 (4096x512)
    u16* qkvb = (u16*)p;  p += (size_t)6291456 * 2;  // qkv bf16 (4096x1536)
    u16* attb = (u16*)p;  p += (size_t)2097152 * 2;  // attn out bf16 (4096x512)
    u16* x2b  = (u16*)p;  p += (size_t)2097152 * 2;  // x + proj(attn), bf16
    u16* mb   = (u16*)p;  p += (size_t)8388608 * 2;  // gelu(fc1) bf16 (4096x2048)

    // 1) prep: wq cvt (768) + LN1 (1024)
    prep_kernel<<<1792, 256, 0, stream>>>(qkvw, wq, x, n1w, n1b, hb1);
    // 2) qkv GEMM + wp/w1 cvt tails
    gemm16<0, 0><<<dim3(32, 12 + 40), 256, 0, stream>>>(
        hb1, wq, qkvbv, qkvb, 4096, 1536, 512, 12,
        projw, wp, 256, fc1w, w1, 1024,
        nullptr, nullptr, nullptr, nullptr);
    // 3) attention + w2 cvt tail
    attn_kernel<<<512 + 1024, 256, 0, stream>>>(qkvb, relb, attb, fc2w, w2);
    // 4) proj: x2 = x + attb @ wp^T + b (bf16)
    gemm32<1><<<dim3(64, 8), 256, 0, stream>>>(attb, wp, projb, x, nullptr,
                                               nullptr, x2b, 4096, 512, 512);
    // 5) fc1 + GELU, with fused LN2 prologue (x2b -> hb2, own rows)
    gemm16<2, 2><<<dim3(32, 16), 256, 0, stream>>>(
        hb2, w1, fc1b, mb, 4096, 2048, 512, 16,
        nullptr, nullptr, 0, nullptr, nullptr, 0,
        x2b, n2w, n2b, hb2);
    // 6) fc2: out = x2 + mb @ w2^T + b (fp32)
    gemm32<3><<<dim3(64, 8), 256, 0, stream>>>(mb, w2, fc2b, nullptr, x2b,
                                               out, nullptr, 4096, 512, 2048);
}

// Round 11
// 164.885 us; speedup vs baseline: 2.5782x; 1.0780x over previous
//
#include <hip/hip_runtime.h>

typedef unsigned short u16;
typedef unsigned int uint;
typedef __attribute__((ext_vector_type(4))) float floatx4;
typedef __attribute__((ext_vector_type(16))) float floatx16;
typedef __attribute__((ext_vector_type(8))) short shortx8;

// ---------- helpers ----------
__device__ __forceinline__ u16 f2b(float f) {
    unsigned int u = __float_as_uint(f);
    unsigned int r = (u + 0x7fffu + ((u >> 16) & 1u)) >> 16;
    return (u16)r;
}
__device__ __forceinline__ float b2f(u16 u) {
    return __uint_as_float(((unsigned int)u) << 16);
}
__device__ __forceinline__ void gl_lds16(const u16* g, u16* l) {
    __builtin_amdgcn_global_load_lds(
        (const __attribute__((address_space(1))) void*)g,
        (__attribute__((address_space(3))) void*)l, 16, 0, 0);
}
__device__ __forceinline__ float gelu_f(float v) {
    float e = __expf(1.59576912f * v * (1.0f + 0.044715f * v * v));
    return v * e / (e + 1.0f);
}
// one 1024-float4 weight-cvt chunk (f32 -> bf16), 256 threads
__device__ __forceinline__ void cvt_block(const float* __restrict__ src,
                                          u16* __restrict__ dst, int i0) {
    int i = i0 * 256 + threadIdx.x;
    float4 v = ((const float4*)src)[i];
    uint2 o;
    o.x = (uint)f2b(v.x) | ((uint)f2b(v.y) << 16);
    o.y = (uint)f2b(v.z) | ((uint)f2b(v.w) << 16);
    ((uint2*)dst)[i] = o;
}

// ---------- wave-per-row LN (C=512): 8 elems/lane, shuffle-only ----------
__device__ __forceinline__ void ln_row_wave_f32(const float* __restrict__ x,
                                                const float* __restrict__ w,
                                                const float* __restrict__ b,
                                                u16* __restrict__ out, int row) {
    int lane = threadIdx.x & 63;
    const float4* xr = (const float4*)(x + (size_t)row * 512);
    float4 v0 = xr[lane * 2], v1 = xr[lane * 2 + 1];
    float s = v0.x + v0.y + v0.z + v0.w + v1.x + v1.y + v1.z + v1.w;
    float s2 = v0.x * v0.x + v0.y * v0.y + v0.z * v0.z + v0.w * v0.w +
               v1.x * v1.x + v1.y * v1.y + v1.z * v1.z + v1.w * v1.w;
    #pragma unroll
    for (int o = 32; o > 0; o >>= 1) {
        s += __shfl_xor(s, o, 64);
        s2 += __shfl_xor(s2, o, 64);
    }
    float mu = s * (1.0f / 512.0f);
    float var = s2 * (1.0f / 512.0f) - mu * mu;
    float rstd = rsqrtf(var + 1e-5f);
    const float4* wr = (const float4*)w;
    const float4* br = (const float4*)b;
    float4 w0 = wr[lane * 2], w1 = wr[lane * 2 + 1];
    float4 b0 = br[lane * 2], b1 = br[lane * 2 + 1];
    uint4 o4;
    o4.x = (uint)f2b((v0.x - mu) * rstd * w0.x + b0.x) |
           ((uint)f2b((v0.y - mu) * rstd * w0.y + b0.y) << 16);
    o4.y = (uint)f2b((v0.z - mu) * rstd * w0.z + b0.z) |
           ((uint)f2b((v0.w - mu) * rstd * w0.w + b0.w) << 16);
    o4.z = (uint)f2b((v1.x - mu) * rstd * w1.x + b1.x) |
           ((uint)f2b((v1.y - mu) * rstd * w1.y + b1.y) << 16);
    o4.w = (uint)f2b((v1.z - mu) * rstd * w1.z + b1.z) |
           ((uint)f2b((v1.w - mu) * rstd * w1.w + b1.w) << 16);
    ((uint4*)(out + (size_t)row * 512))[lane] = o4;
}

// ---------- LN2: bf16 input, wave-per-row, 4 rows/block ----------
__global__ __launch_bounds__(256) void ln_kernel_b(const u16* __restrict__ x,
                                                   const float* __restrict__ w,
                                                   const float* __restrict__ b,
                                                   u16* __restrict__ out) {
    int row = blockIdx.x * 4 + (threadIdx.x >> 6);
    int lane = threadIdx.x & 63;
    uint4 p = ((const uint4*)(x + (size_t)row * 512))[lane];
    float v[8];
    v[0] = b2f((u16)(p.x & 0xffffu)); v[1] = b2f((u16)(p.x >> 16));
    v[2] = b2f((u16)(p.y & 0xffffu)); v[3] = b2f((u16)(p.y >> 16));
    v[4] = b2f((u16)(p.z & 0xffffu)); v[5] = b2f((u16)(p.z >> 16));
    v[6] = b2f((u16)(p.w & 0xffffu)); v[7] = b2f((u16)(p.w >> 16));
    float s = 0.f, s2 = 0.f;
    #pragma unroll
    for (int i = 0; i < 8; i++) { s += v[i]; s2 += v[i] * v[i]; }
    #pragma unroll
    for (int o = 32; o > 0; o >>= 1) {
        s += __shfl_xor(s, o, 64);
        s2 += __shfl_xor(s2, o, 64);
    }
    float mu = s * (1.0f / 512.0f);
    float var = s2 * (1.0f / 512.0f) - mu * mu;
    float rstd = rsqrtf(var + 1e-5f);
    const float4* wr = (const float4*)w;
    const float4* br = (const float4*)b;
    float4 w0 = wr[lane * 2], w1 = wr[lane * 2 + 1];
    float4 b0 = br[lane * 2], b1 = br[lane * 2 + 1];
    float o8[8];
    o8[0] = (v[0] - mu) * rstd * w0.x + b0.x;
    o8[1] = (v[1] - mu) * rstd * w0.y + b0.y;
    o8[2] = (v[2] - mu) * rstd * w0.z + b0.z;
    o8[3] = (v[3] - mu) * rstd * w0.w + b0.w;
    o8[4] = (v[4] - mu) * rstd * w1.x + b1.x;
    o8[5] = (v[5] - mu) * rstd * w1.y + b1.y;
    o8[6] = (v[6] - mu) * rstd * w1.z + b1.z;
    o8[7] = (v[7] - mu) * rstd * w1.w + b1.w;
    uint4 o4;
    o4.x = (uint)f2b(o8[0]) | ((uint)f2b(o8[1]) << 16);
    o4.y = (uint)f2b(o8[2]) | ((uint)f2b(o8[3]) << 16);
    o4.z = (uint)f2b(o8[4]) | ((uint)f2b(o8[5]) << 16);
    o4.w = (uint)f2b(o8[6]) | ((uint)f2b(o8[7]) << 16);
    ((uint4*)(out + (size_t)row * 512))[lane] = o4;
}

// ---------- prep: cvt wq + LN1 (R8/R10 lesson: keep standalone — fusion
// re-prices redundant reads at HBM rates and redundant writes at coherence
// rates; both measured losers) ----------
__global__ __launch_bounds__(256) void prep_kernel(
    const float* __restrict__ qkvw, u16* __restrict__ wq,
    const float* __restrict__ x, const float* __restrict__ n1w,
    const float* __restrict__ n1b, u16* __restrict__ hb) {
    int bi = blockIdx.x;
    if (bi < 768) {
        cvt_block(qkvw, wq, bi);
    } else {
        int row = (bi - 768) * 4 + (threadIdx.x >> 6);
        ln_row_wave_f32(x, n1w, n1b, hb, row);
    }
}

// ---------- GEMM A: 16x16x32 MFMA, MI=NI=4 (m97 frag reuse), dbuf ----------
// 128x128 block, BK=64, 2x2 waves. EPI: 0 bias->bf16 | 2 bias+GELU->bf16
// Grid rows by >= nby are weight-cvt tail blocks.
template <int EPI>
__global__ __launch_bounds__(256, 2) void gemm16(const u16* __restrict__ A,
                                                 const u16* __restrict__ W,
                                                 const float* __restrict__ bias,
                                                 u16* __restrict__ outB,
                                                 int M, int Nn, int K, int nby,
                                                 const float* __restrict__ cs0,
                                                 u16* __restrict__ cd0, int cn0,
                                                 const float* __restrict__ cs1,
                                                 u16* __restrict__ cd1, int cn1) {
    constexpr int BM = 128, BN = 128, BK = 64;
    __shared__ u16 a_s[2][BM * BK];
    __shared__ u16 b_s[2][BN * BK];

    if ((int)blockIdx.y >= nby) {
        int flat = ((int)blockIdx.y - nby) * (int)gridDim.x + (int)blockIdx.x;
        if (flat < cn0)            cvt_block(cs0, cd0, flat);
        else if (flat < cn0 + cn1) cvt_block(cs1, cd1, flat - cn0);
        return;
    }

    int tid = threadIdx.x;
    int wid = tid >> 6, lane = tid & 63;
    int wm = wid >> 1, wn = wid & 1;
    int m_blk = blockIdx.x * BM;
    int n_blk = blockIdx.y * BN;
    int lr = lane & 15;
    int lkc = lane >> 4;

    floatx4 acc[4][4];
    #pragma unroll
    for (int i = 0; i < 4; i++)
        #pragma unroll
        for (int j = 0; j < 4; j++) acc[i][j] = (floatx4){0.f, 0.f, 0.f, 0.f};

    const u16* Ag = A + (size_t)m_blk * K;
    const u16* Wg = W + (size_t)n_blk * K;

    int srow = tid >> 3;
    int skc = (tid & 7) ^ (srow & 7);

    auto stage = [&](int k0, int buf) {
        #pragma unroll
        for (int p = 0; p < 4; p++)
            gl_lds16(Ag + (size_t)(p * 32 + srow) * K + k0 + skc * 8,
                     a_s[buf] + (p * 256 + tid) * 8);
        #pragma unroll
        for (int p = 0; p < 4; p++)
            gl_lds16(Wg + (size_t)(p * 32 + srow) * K + k0 + skc * 8,
                     b_s[buf] + (p * 256 + tid) * 8);
    };

    stage(0, 0);
    int nit = K >> 6;
    for (int it = 0; it < nit; it++) {
        __syncthreads();
        if (it + 1 < nit) stage((it + 1) << 6, (it + 1) & 1);
        int cb = it & 1;
        #pragma unroll
        for (int s = 0; s < 2; s++) {
            int kc = s * 4 + lkc;
            shortx8 af[4], bf[4];
            #pragma unroll
            for (int i = 0; i < 4; i++) {
                int row = wm * 64 + i * 16 + lr;
                af[i] = *(const shortx8*)(a_s[cb] + (row * 8 + (kc ^ (row & 7))) * 8);
            }
            #pragma unroll
            for (int j = 0; j < 4; j++) {
                int row = wn * 64 + j * 16 + lr;
                bf[j] = *(const shortx8*)(b_s[cb] + (row * 8 + (kc ^ (row & 7))) * 8);
            }
            #pragma unroll
            for (int i = 0; i < 4; i++)
                #pragma unroll
                for (int j = 0; j < 4; j++)
                    acc[i][j] = __builtin_amdgcn_mfma_f32_16x16x32_bf16(
                        af[i], bf[j], acc[i][j], 0, 0, 0);
        }
    }

    int col_l = lane & 15;
    int row_base = (lane >> 4) * 4;
    #pragma unroll
    for (int nj = 0; nj < 4; nj++) {
        int col = n_blk + wn * 64 + nj * 16 + col_l;
        float bv = bias[col];
        #pragma unroll
        for (int mi = 0; mi < 4; mi++) {
            #pragma unroll
            for (int r = 0; r < 4; r++) {
                int row = m_blk + wm * 64 + mi * 16 + row_base + r;
                size_t off = (size_t)row * Nn + col;
                float v = acc[mi][nj][r] + bv;
                outB[off] = f2b(EPI == 2 ? gelu_f(v) : v);
            }
        }
    }
}

// ---------- GEMM B: 64x64 block, BK=128, dbuf — now 16x16x32 MFMA 2x2 ------
// R7 counters: old 1-tile/wave 32x32 form = 2.0 ds_read_b128/MFMA ->
// MfmaUtil 21%, LDS-read-bound (24cy LDS : 8cy MFMA per step, m134).
// New: wave tile 32x32 as 2x2 16-tiles -> 4 reads feed 4 MFMAs
// (1.0 reads/MFMA). Geometry/staging/swizzle/occupancy UNCHANGED.
// EPI: 1 bias+residF32->bf16 | 3 bias+residB16->fp32 (d_out)
template <int EPI>
__global__ __launch_bounds__(256, 2) void gemm32(const u16* __restrict__ A,
                                                 const u16* __restrict__ W,
                                                 const float* __restrict__ bias,
                                                 const float* __restrict__ residF,
                                                 const u16* __restrict__ residB,
                                                 float* __restrict__ outF,
                                                 u16* __restrict__ outB,
                                                 int M, int Nn, int K) {
    constexpr int BM = 64, BN = 64, BK = 128;
    constexpr int CPR = BK / 8, KMSK = CPR - 1;   // 16 chunks/row, mask 15
    __shared__ u16 a_s[2][BM * BK];
    __shared__ u16 b_s[2][BN * BK];

    int tid = threadIdx.x;
    int wid = tid >> 6, lane = tid & 63;
    int wm = wid >> 1, wn = wid & 1;
    int m_blk = blockIdx.x * BM;
    int n_blk = blockIdx.y * BN;
    int lr = lane & 15;          // row-in-16-tile
    int lkc = lane >> 4;         // 0..3: 8-elem K-subchunk within K=32

    floatx4 acc[2][2];
    #pragma unroll
    for (int i = 0; i < 2; i++)
        #pragma unroll
        for (int j = 0; j < 2; j++) acc[i][j] = (floatx4){0.f, 0.f, 0.f, 0.f};

    const u16* Ag = A + (size_t)m_blk * K;
    const u16* Wg = W + (size_t)n_blk * K;

    int srow = tid / CPR;
    int skc = (tid & KMSK) ^ (srow & KMSK);

    auto stage = [&](int k0, int buf) {
        #pragma unroll
        for (int p = 0; p < 4; p++)
            gl_lds16(Ag + (size_t)(p * 16 + srow) * K + k0 + skc * 8,
                     a_s[buf] + (p * 256 + tid) * 8);
        #pragma unroll
        for (int p = 0; p < 4; p++)
            gl_lds16(Wg + (size_t)(p * 16 + srow) * K + k0 + skc * 8,
                     b_s[buf] + (p * 256 + tid) * 8);
    };

    stage(0, 0);
    int nit = K / BK;
    for (int it = 0; it < nit; it++) {
        __syncthreads();
        if (it + 1 < nit) stage((it + 1) * BK, (it + 1) & 1);
        int cb = it & 1;
        #pragma unroll
        for (int s = 0; s < 4; s++) {            // four K=32 sub-tiles
            int kc = s * 4 + lkc;
            shortx8 af[2], bf[2];
            #pragma unroll
            for (int i = 0; i < 2; i++) {
                int arow = wm * 32 + i * 16 + lr;
                af[i] = *(const shortx8*)(a_s[cb] + (arow * CPR + (kc ^ (arow & KMSK))) * 8);
            }
            #pragma unroll
            for (int j = 0; j < 2; j++) {
                int brow = wn * 32 + j * 16 + lr;
                bf[j] = *(const shortx8*)(b_s[cb] + (brow * CPR + (kc ^ (brow & KMSK))) * 8);
            }
            #pragma unroll
            for (int i = 0; i < 2; i++)
                #pragma unroll
                for (int j = 0; j < 2; j++)
                    acc[i][j] = __builtin_amdgcn_mfma_f32_16x16x32_bf16(
                        af[i], bf[j], acc[i][j], 0, 0, 0);
        }
    }

    // 16x16 C/D: col = lane&15, row = (lane>>4)*4 + r
    int col_l = lane & 15;
    int row_base = (lane >> 4) * 4;
    #pragma unroll
    for (int j = 0; j < 2; j++) {
        int col = n_blk + wn * 32 + j * 16 + col_l;
        float bv = bias[col];
        #pragma unroll
        for (int i = 0; i < 2; i++) {
            #pragma unroll
            for (int r = 0; r < 4; r++) {
                int row = m_blk + wm * 32 + i * 16 + row_base + r;
                size_t off = (size_t)row * Nn + col;
                float v = acc[i][j][r] + bv;
                if (EPI == 1) outB[off] = f2b(v + residF[off]);
                else          outF[off] = v + b2f(residB[off]);
            }
        }
    }
}

// ---------- windowed attention, MFMA flash-style ----------
// LDS strides chosen for bank spread (word-stride mod 32):
//  k_s [76], v_t [154], p_s [106] — R6-verified layout.
// Grid tail blocks (bx >= 512) convert fc2 weights (overlap with attn).
__global__ __launch_bounds__(256) void attn_kernel(const u16* __restrict__ qkv,
                                                   const float* __restrict__ rel_bias,
                                                   u16* __restrict__ out,
                                                   const float* __restrict__ csrc,
                                                   u16* __restrict__ cdst) {
    __shared__ u16 k_s[128][76];
    __shared__ u16 v_t[64][154];
    __shared__ u16 p_s[4][16][106];
    __shared__ float s_bias[64];

    int bx = blockIdx.x;
    if (bx >= 512) {                      // weight-cvt tail (w2)
        cvt_block(csrc, cdst, bx - 512);
        return;
    }
    int n = bx >> 8;
    int h = (bx >> 5) & 7;
    int t0 = (bx & 31) << 6;
    int tid = threadIdx.x, wid = tid >> 6, lane = tid & 63;
    int col = lane & 15, rq = lane >> 4;

    const u16* qrow = qkv + (size_t)(n * 2048 + t0 + wid * 16 + col) * 1536 + h * 64 + rq * 8;
    shortx8 qf0 = *(const shortx8*)qrow;
    shortx8 qf1 = *(const shortx8*)(qrow + 32);

    if (tid < 63) s_bias[tid] = rel_bias[h * 63 + tid];
    if (tid == 63) s_bias[63] = 0.f;

    const uint* qkv_u = (const uint*)qkv;
    // K tile: vectorized uint2 loads (8B/lane), 8 iters
    for (int idx = tid; idx < 128 * 16; idx += 256) {
        int row = idx >> 4, j2 = idx & 15;
        int pos = t0 - 31 + row;
        uint2 kv; kv.x = 0u; kv.y = 0u;
        if (pos >= 0 && pos < 2048)
            kv = *(const uint2*)(qkv_u + (size_t)(n * 2048 + pos) * 768 + 256 + h * 32 + j2 * 2);
        *(uint2*)&k_s[row][j2 * 4] = kv;
    }
    // V transpose: row-pairs, packed b32 LDS writes
    for (int idx = tid; idx < 72 * 32; idx += 256) {
        int rp = idx >> 5, j = idx & 31;
        int r0 = rp * 2;
        int p0 = t0 - 31 + r0, p1 = p0 + 1;
        uint a = 0u, b = 0u;
        if (p0 >= 0 && p0 < 2048)
            a = qkv_u[(size_t)(n * 2048 + p0) * 768 + 512 + h * 32 + j];
        if (p1 >= 0 && p1 < 2048)
            b = qkv_u[(size_t)(n * 2048 + p1) * 768 + 512 + h * 32 + j];
        *(uint*)&v_t[2 * j][r0]     = (a & 0xffffu) | (b << 16);
        *(uint*)&v_t[2 * j + 1][r0] = (a >> 16) | (b & 0xffff0000u);
    }
    __syncthreads();

    floatx4 S[5];
    #pragma unroll
    for (int nt = 0; nt < 5; nt++) S[nt] = (floatx4){0.f, 0.f, 0.f, 0.f};
    #pragma unroll
    for (int nt = 0; nt < 5; nt++) {
        const u16* kb = &k_s[wid * 16 + nt * 16 + col][rq * 8];
        shortx8 b0 = *(const shortx8*)kb;
        shortx8 b1 = *(const shortx8*)(kb + 32);
        S[nt] = __builtin_amdgcn_mfma_f32_16x16x32_bf16(qf0, b0, S[nt], 0, 0, 0);
        S[nt] = __builtin_amdgcn_mfma_f32_16x16x32_bf16(qf1, b1, S[nt], 0, 0, 0);
    }

    #pragma unroll
    for (int r = 0; r < 4; r++) {
        int t_row = rq * 4 + r;
        float sc[5];
        float mx = -1e30f;
        #pragma unroll
        for (int nt = 0; nt < 5; nt++) {
            int w = nt * 16 + col - t_row;
            int pos_abs = t0 - 31 + wid * 16 + nt * 16 + col;
            float v;
            if (w < 0 || w > 62) {
                v = -1e30f;
            } else {
                v = S[nt][r] * 0.125f + s_bias[w];
                if (pos_abs < 0 || pos_abs >= 2048) v -= 100.f;
            }
            sc[nt] = v;
            mx = fmaxf(mx, v);
        }
        #pragma unroll
        for (int o = 1; o < 16; o <<= 1) mx = fmaxf(mx, __shfl_xor(mx, o, 64));
        float l = 0.f;
        #pragma unroll
        for (int nt = 0; nt < 5; nt++) {
            sc[nt] = __expf(sc[nt] - mx);
            l += sc[nt];
        }
        #pragma unroll
        for (int o = 1; o < 16; o <<= 1) l += __shfl_xor(l, o, 64);
        float inv = 1.0f / l;
        #pragma unroll
        for (int nt = 0; nt < 5; nt++)
            p_s[wid][t_row][nt * 16 + col] = f2b(sc[nt] * inv);
        p_s[wid][t_row][80 + col] = 0;
    }
    __syncthreads();

    floatx4 O[4];
    #pragma unroll
    for (int dt = 0; dt < 4; dt++) O[dt] = (floatx4){0.f, 0.f, 0.f, 0.f};
    const u16* pr = &p_s[wid][col][rq * 8];
    shortx8 a0 = *(const shortx8*)pr;
    shortx8 a1 = *(const shortx8*)(pr + 32);
    shortx8 a2 = *(const shortx8*)(pr + 64);
    #pragma unroll
    for (int dt = 0; dt < 4; dt++) {
        const u16* vb = &v_t[dt * 16 + col][wid * 16 + rq * 8];
        shortx8 b0 = *(const shortx8*)vb;
        shortx8 b1 = *(const shortx8*)(vb + 32);
        shortx8 b2 = *(const shortx8*)(vb + 64);
        O[dt] = __builtin_amdgcn_mfma_f32_16x16x32_bf16(a0, b0, O[dt], 0, 0, 0);
        O[dt] = __builtin_amdgcn_mfma_f32_16x16x32_bf16(a1, b1, O[dt], 0, 0, 0);
        O[dt] = __builtin_amdgcn_mfma_f32_16x16x32_bf16(a2, b2, O[dt], 0, 0, 0);
    }

    #pragma unroll
    for (int dt = 0; dt < 4; dt++) {
        #pragma unroll
        for (int r = 0; r < 4; r++) {
            int t_row = rq * 4 + r;
            out[(size_t)(n * 2048 + t0 + wid * 16 + t_row) * 512 + h * 64 + dt * 16 + col] =
                f2b(O[dt][r]);
        }
    }
}

// ---------- launcher: R6 structure (7 kernels, overlapped cvt) ----------
extern "C" void kernel_launch(void* const* d_in, const int* in_sizes, int n_in,
                              void* d_out, int out_size, void* d_ws, size_t ws_size,
                              hipStream_t stream) {
    const float* x     = (const float*)d_in[0];
    const float* n1w   = (const float*)d_in[1];
    const float* n1b   = (const float*)d_in[2];
    const float* qkvw  = (const float*)d_in[3];
    const float* qkvbv = (const float*)d_in[4];
    const float* relb  = (const float*)d_in[5];
    const float* projw = (const float*)d_in[6];
    const float* projb = (const float*)d_in[7];
    const float* n2w   = (const float*)d_in[8];
    const float* n2b   = (const float*)d_in[9];
    const float* fc1w  = (const float*)d_in[10];
    const float* fc1b  = (const float*)d_in[11];
    const float* fc2w  = (const float*)d_in[12];
    const float* fc2b  = (const float*)d_in[13];
    float* out = (float*)d_out;

    char* p = (char*)d_ws;
    u16* wq   = (u16*)p;  p += (size_t)786432 * 2;   // qkv_w bf16 (1536x512)
    u16* wp   = (u16*)p;  p += (size_t)262144 * 2;   // proj_w bf16 (512x512)
    u16* w1   = (u16*)p;  p += (size_t)1048576 * 2;  // fc1_w bf16 (2048x512)
    u16* w2   = (u16*)p;  p += (size_t)1048576 * 2;  // fc2_w bf16 (512x2048)
    u16* hb   = (u16*)p;  p += (size_t)2097152 * 2;  // h / h2 bf16 (4096x512)
    u16* qkvb = (u16*)p;  p += (size_t)6291456 * 2;  // qkv bf16 (4096x1536)
    u16* attb = (u16*)p;  p += (size_t)2097152 * 2;  // attn out bf16 (4096x512)
    u16* x2b  = (u16*)p;  p += (size_t)2097152 * 2;  // x + proj(attn), bf16
    u16* mb   = (u16*)p;  p += (size_t)8388608 * 2;  // gelu(fc1) bf16 (4096x2048)

    // phase 0: wq cvt (768) + LN1 (1024)
    prep_kernel<<<1792, 256, 0, stream>>>(qkvw, wq, x, n1w, n1b, hb);
    // phase 1: qkv GEMM (32x12) + wp cvt (256) + w1 cvt (1024) tail
    gemm16<0><<<dim3(32, 12 + 40), 256, 0, stream>>>(hb, wq, qkvbv, qkvb,
                                                     4096, 1536, 512, 12,
                                                     projw, wp, 256,
                                                     fc1w, w1, 1024);
    // phase 2: attention (512) + w2 cvt (1024) tail
    attn_kernel<<<512 + 1024, 256, 0, stream>>>(qkvb, relb, attb, fc2w, w2);
    // phase 3: proj: x2 = x + proj (bf16)
    gemm32<1><<<dim3(64, 8), 256, 0, stream>>>(attb, wp, projb, x, nullptr,
                                               nullptr, x2b, 4096, 512, 512);
    // phase 4: LN2
    ln_kernel_b<<<1024, 256, 0, stream>>>(x2b, n2w, n2b, hb);
    // phase 5: fc1 + GELU
    gemm16<2><<<dim3(32, 16), 256, 0, stream>>>(hb, w1, fc1b, mb,
                                                4096, 2048, 512, 16,
                                                nullptr, nullptr, 0,
                                                nullptr, nullptr, 0);
    // phase 6: fc2: out = x2 + fc2 (fp32)
    gemm32<3><<<dim3(64, 8), 256, 0, stream>>>(mb, w2, fc2b, nullptr, x2b,
                                               out, nullptr, 4096, 512, 2048);
}